// Round 3
// baseline (314.527 us; speedup 1.0000x reference)
//
#include <hip/hip_runtime.h>
#include <math.h>

#define NN 500
#define NE 64
#define BATCH 8
#define RR 15
#define PW 31            // 2R+1
#define CAN 200
#define OHW 198
#define TWO_PI_F 6.28318530717958647692f

// ---------------------------------------------------------------------------
// K0: build pupil field, K*GAMMA table, and 500-pt twiddle table
// ---------------------------------------------------------------------------
__global__ void k_init(const float* __restrict__ phase,
                       float2* __restrict__ field,
                       float* __restrict__ kgamma,
                       float2* __restrict__ tw) {
    int idx = blockIdx.x * blockDim.x + threadIdx.x;
    if (idx < NN) {
        double th = 2.0 * M_PI * (double)idx / (double)NN;
        tw[idx] = make_float2((float)cos(th), (float)sin(th));
    }
    if (idx >= NN * NN) return;
    int i = idx / NN, j = idx % NN;

    double x = (double)(j - 250) * 1e-6;
    double y = (double)(i - 250) * 1e-6;
    double r2 = x * x + y * y;
    double inc_d = exp(-r2 / (2.0 * 1.5e-4 * 1.5e-4));
    double c1 = fmod(M_PI / (5.32e-7 * 0.1) * r2, 2.0 * M_PI);
    float inc = (float)inc_d;
    float b1r = (float)cos(c1);
    float b1i = (float)(-sin(c1));
    float ph = phase[idx];
    float sp, cp;
    sincosf(ph, &sp, &cp);
    float ar = inc * cp, ai = inc * sp;
    field[idx] = make_float2(ar * b1r - ai * b1i, ar * b1i + ai * b1r);

    double fy = (double)((i < 250) ? i : i - 500) * 2000.0;
    double fx = (double)((j < 250) ? j : j - 500) * 2000.0;
    double a = 5.32e-7 * fx;
    double b = 5.32e-7 * fy;
    double g = 1.0 - a * a - b * b;
    g = (g > 0.0) ? sqrt(g) : 0.0;
    float Kf = (float)(2.0 * M_PI * 1.0 / 5.32e-7);
    kgamma[idx] = Kf * (float)g;
}

// ---------------------------------------------------------------------------
// Full 500-pt DFT along one axis, pair trick (k and k+250 share a rotator via
// (-1)^n), rotation recurrence with exact-table resync every 64 n.
// ---------------------------------------------------------------------------
__global__ void k_dft500(const float2* __restrict__ src, float2* __restrict__ dst,
                         const float2* __restrict__ tw,
                         int src_line, int src_elem, int dst_line, int dst_elem,
                         float sgn) {
    __shared__ __align__(16) float2 xs[NN];
    __shared__ float2 tts[NN];
    int line = blockIdx.x;
    const float2* s = src + (size_t)line * src_line;
    for (int n = threadIdx.x; n < NN; n += blockDim.x) {
        xs[n] = s[(size_t)n * src_elem];
        float2 t = tw[n];
        tts[n] = make_float2(t.x, sgn * t.y);
    }
    __syncthreads();
    int k = threadIdx.x;
    if (k < 250) {
        float2 s1 = tts[k];
        float wr = 1.f, wi = 0.f;
        float a1r = 0.f, a1i = 0.f, a2r = 0.f, a2i = 0.f;
        for (int n = 0; n < NN; n += 2) {
            if ((n & 63) == 0) {   // resync rotator from exact table
                int idx = (n * k) % NN;
                float2 e = tts[idx];
                wr = e.x; wi = e.y;
            }
            float4 xy = *(const float4*)&xs[n];   // xs[n], xs[n+1]
            float tr = wr * s1.x - wi * s1.y;     // twiddle at n+1
            float ti = wr * s1.y + wi * s1.x;
            float pr = xy.x * wr - xy.y * wi;
            float pi = xy.x * wi + xy.y * wr;
            float qr = xy.z * tr - xy.w * ti;
            float qi = xy.z * ti + xy.w * tr;
            a1r += pr + qr;  a1i += pi + qi;
            a2r += pr - qr;  a2i += pi - qi;      // output k+250: *(-1)^n
            wr = tr * s1.x - ti * s1.y;           // advance to n+2
            wi = tr * s1.y + ti * s1.x;
        }
        float2* d = dst + (size_t)line * dst_line;
        d[(size_t)k * dst_elem] = make_float2(a1r, a1i);
        d[(size_t)(k + 250) * dst_elem] = make_float2(a2r, a2i);
    }
}

// ---------------------------------------------------------------------------
// B1 v3: block = (u, zhalf). 4 passes of 8 z. Thread = (cq in [0,8), sl in
// [0,8)) per wave; each thread accumulates C=4 c-values x Z=8 z-planes so one
// LDS read of Ys[z][v] feeds 16 FMAs. v0 = sl + 8*wave, stride 32.
//   part[z][c][u] = sum_v Ef[u,v]*e^{i*kg[u,v]*z} * e^{+2pi*i*v*c/500}
// ---------------------------------------------------------------------------
__global__ void __launch_bounds__(256, 3)
k_prop_rows(const float2* __restrict__ Ef,
            const float* __restrict__ kgamma,
            const float* __restrict__ zs,
            float2* __restrict__ part) {
    __shared__ float2 Ys[8][NN];      // 32000 B
    __shared__ float2 efs[NN];        // 4000 B
    __shared__ float  kgs[NN];        // 2000 B
    __shared__ float2 red[32][4][8];  // 8192 B
    int u = blockIdx.x;
    int zhalf = blockIdx.y;
    int t = threadIdx.x;
    int w = t >> 6, lane = t & 63;
    int cq = lane & 7, sl = lane >> 3;
    int v0 = sl + 8 * w;              // 0..31

    const float2* erow = Ef + (size_t)u * NN;
    const float* grow = kgamma + (size_t)u * NN;
    for (int v = t; v < NN; v += 256) {
        efs[v] = erow[v];
        kgs[v] = grow[v];
    }

    // per-(cl) rotator init (depends only on v0,c -> pass-independent)
    float w0r[4], w0i[4], str[4], sti[4];
#pragma unroll
    for (int cl = 0; cl < 4; ++cl) {
        int c = 235 + cq * 4 + cl;
        float th0 = (TWO_PI_F / NN) * (float)((v0 * c) % NN);
        sincosf(th0, &w0i[cl], &w0r[cl]);
        float ths = (TWO_PI_F / NN) * (float)((32 * c) % NN);
        sincosf(ths, &sti[cl], &str[cl]);
    }
    __syncthreads();

    for (int g = 0; g < 4; ++g) {
        int zbase = zhalf * 32 + g * 8;
        float zv[8];
#pragma unroll
        for (int zi = 0; zi < 8; ++zi) zv[zi] = zs[zbase + zi];
        // modulate: Ys[zi][v] = efs[v] * e^{i*kgs[v]*z}
        for (int v = t; v < NN; v += 256) {
            float2 e = efs[v];
            float kg = kgs[v];
#pragma unroll
            for (int zi = 0; zi < 8; ++zi) {
                float s, cc;
                sincosf(kg * zv[zi], &s, &cc);
                Ys[zi][v] = make_float2(e.x * cc - e.y * s, e.x * s + e.y * cc);
            }
        }
        __syncthreads();

        // DFT: C=4 x Z=8 accumulators per thread
        float wr[4], wi[4];
#pragma unroll
        for (int cl = 0; cl < 4; ++cl) { wr[cl] = w0r[cl]; wi[cl] = w0i[cl]; }
        float accr[4][8], acci[4][8];
#pragma unroll
        for (int cl = 0; cl < 4; ++cl)
#pragma unroll
            for (int zi = 0; zi < 8; ++zi) { accr[cl][zi] = 0.f; acci[cl][zi] = 0.f; }

        for (int v = v0; v < NN; v += 32) {
            float2 xv[8];
#pragma unroll
            for (int zi = 0; zi < 8; ++zi) xv[zi] = Ys[zi][v];
#pragma unroll
            for (int cl = 0; cl < 4; ++cl) {
                float cwr = wr[cl], cwi = wi[cl];
#pragma unroll
                for (int zi = 0; zi < 8; ++zi) {
                    accr[cl][zi] += xv[zi].x * cwr - xv[zi].y * cwi;
                    acci[cl][zi] += xv[zi].x * cwi + xv[zi].y * cwr;
                }
                wr[cl] = cwr * str[cl] - cwi * sti[cl];
                wi[cl] = cwr * sti[cl] + cwi * str[cl];
            }
        }

        // in-wave reduce over sl (lane bits 3..5)
#pragma unroll
        for (int cl = 0; cl < 4; ++cl)
#pragma unroll
            for (int zi = 0; zi < 8; ++zi) {
#pragma unroll
                for (int m = 8; m < 64; m <<= 1) {
                    accr[cl][zi] += __shfl_xor(accr[cl][zi], m);
                    acci[cl][zi] += __shfl_xor(acci[cl][zi], m);
                }
            }
        if (sl == 0) {
#pragma unroll
            for (int cl = 0; cl < 4; ++cl)
#pragma unroll
                for (int zi = 0; zi < 8; ++zi)
                    red[w * 8 + cq][cl][zi] = make_float2(accr[cl][zi], acci[cl][zi]);
        }
        __syncthreads();

        // combine 4 wave-partials and store
        if (t < PW * 8) {
            int ci = t >> 3, zi = t & 7;
            int cqq = ci >> 2, cll = ci & 3;
            float sr_ = 0.f, si_ = 0.f;
#pragma unroll
            for (int ww = 0; ww < 4; ++ww) {
                float2 p = red[ww * 8 + cqq][cll][zi];
                sr_ += p.x; si_ += p.y;
            }
            part[((size_t)(zbase + zi) * PW + ci) * NN + u] = make_float2(sr_, si_);
        }
        __syncthreads();
    }
}

// ---------------------------------------------------------------------------
// B2: per (z,c): Eprop[r,c] = (1/500^2) * sum_u part[z][c][u]*e^{+2pi*i*u*r/500}
// ---------------------------------------------------------------------------
__global__ void k_prop_cols(const float2* __restrict__ part,
                            float* __restrict__ psf) {
    __shared__ float2 X[NN];
    int ci = blockIdx.x;   // 31
    int z = blockIdx.y;    // 64
    int t = threadIdx.x;
    const float2* col = part + ((size_t)z * PW + ci) * NN;
    for (int u = t; u < NN; u += 256) X[u] = col[u];
    __syncthreads();
    if (t < PW * 8) {
        int ri = t >> 3, seg = t & 7;
        int r = 235 + ri;
        float wr, wi, sr, si;
        {
            float th0 = (TWO_PI_F / NN) * (float)((seg * r) % NN);
            sincosf(th0, &wi, &wr);
            float ths = (TWO_PI_F / NN) * (float)((8 * r) % NN);
            sincosf(ths, &si, &sr);
        }
        float ar = 0.f, ai = 0.f;
        for (int u = seg; u < NN; u += 8) {
            float2 xv = X[u];
            ar += xv.x * wr - xv.y * wi;
            ai += xv.x * wi + xv.y * wr;
            float nwr = wr * sr - wi * si;
            wi = wr * si + wi * sr;
            wr = nwr;
        }
#pragma unroll
        for (int m = 1; m < 8; m <<= 1) {
            ar += __shfl_xor(ar, m);
            ai += __shfl_xor(ai, m);
        }
        if (seg == 0 && ri < PW) {
            const float inv = 1.0f / 250000.0f;
            float re = ar * inv, im = ai * inv;
            psf[(size_t)z * (PW * PW) + ri * PW + ci] = re * re + im * im;
        }
    }
}

// ---------------------------------------------------------------------------
__global__ void k_norm(const float* __restrict__ psf, float* __restrict__ scales) {
    __shared__ float red[256];
    int z = blockIdx.x;
    float s = 0.f;
    for (int p = threadIdx.x; p < PW * PW; p += 256) s += psf[z * PW * PW + p];
    red[threadIdx.x] = s;
    __syncthreads();
    for (int o = 128; o > 0; o >>= 1) {
        if (threadIdx.x < o) red[threadIdx.x] += red[threadIdx.x + o];
        __syncthreads();
    }
    if (threadIdx.x == 0) scales[z] = 1.0e6f / (red[0] + 1e-12f);
}

__global__ void k_kern(const float* __restrict__ std_u, float* __restrict__ kern) {
    int t = threadIdx.x;
    if (t < 49) {
        float stdv = 0.8f + 0.4f * std_u[0];
        float s2 = stdv * stdv;
        int a = t / 7 - 3, b = t % 7 - 3;
        float g = (float)exp(-0.5 * (double)(a * a + b * b));
        kern[t] = (1.0f / (2.0f * (float)M_PI * s2)) * powf(g, 1.0f / s2);
    }
}

__global__ void k_zero(float* __restrict__ p, int n) {
    int i = blockIdx.x * blockDim.x + threadIdx.x;
    if (i < n) p[i] = 0.f;
}

__global__ void k_scatter(const float* __restrict__ psf,
                          const float* __restrict__ scales,
                          const int* __restrict__ xyz,
                          float* __restrict__ canvas) {
    int e = blockIdx.x;
    int b = blockIdx.y;
    int r0 = xyz[(b * NE + e) * 2 + 0] - RR;
    int c0 = xyz[(b * NE + e) * 2 + 1] - RR;
    float sc = scales[e];
    float* cb = canvas + (size_t)b * (CAN * CAN);
    for (int p = threadIdx.x; p < PW * PW; p += blockDim.x) {
        int i = p / PW, j = p % PW;
        atomicAdd(cb + (r0 + i) * CAN + (c0 + j), psf[e * PW * PW + p] * sc);
    }
}

__global__ void k_final(const float* __restrict__ canvas,
                        const float* __restrict__ kern,
                        const float* __restrict__ eps_dark,
                        const float* __restrict__ eps_photon,
                        const float* __restrict__ eps_read,
                        float* __restrict__ out) {
    __shared__ float kk[49];
    if (threadIdx.x < 49) kk[threadIdx.x] = kern[threadIdx.x];
    __syncthreads();
    int idx = blockIdx.x * blockDim.x + threadIdx.x;
    if (idx >= BATCH * OHW * OHW) return;
    int b = idx / (OHW * OHW);
    int rem = idx % (OHW * OHW);
    int i = rem / OHW, j = rem % OHW;
    const float* cb = canvas + (size_t)b * (CAN * CAN);
    float acc = 0.f;
#pragma unroll
    for (int a = 0; a < 7; ++a) {
        int r = i + a - 2;
        if (r < 0 || r >= CAN) continue;
#pragma unroll
        for (int q = 0; q < 7; ++q) {
            int c = j + q - 2;
            if (c < 0 || c >= CAN) continue;
            acc += cb[r * CAN + c] * kk[a * 7 + q];
        }
    }
    float sig = acc * 0.9f;
    float dark = 0.005f + eps_dark[idx] * sqrtf(0.005f);
    float total = fmaxf(sig + dark, 0.0f);
    float noisy = total + eps_photon[idx] * sqrtf(fmaxf(total, 1e-12f));
    float elec = noisy + eps_read[idx] * 1.6f;
    float adu = fminf(fmaxf(elec * 2.0f, 0.0f), 65535.0f);
    float v = (adu <= 10.0f) ? 1.0f : fminf(adu, 4.0e9f);
    out[idx] = v / 4.0e9f;
}

// ---------------------------------------------------------------------------
extern "C" void kernel_launch(void* const* d_in, const int* in_sizes, int n_in,
                              void* d_out, int out_size, void* d_ws, size_t ws_size,
                              hipStream_t stream) {
    const float* phase    = (const float*)d_in[0];
    const float* zs       = (const float*)d_in[1];
    const int*   xyz      = (const int*)d_in[2];
    const float* std_u    = (const float*)d_in[3];
    const float* epsd     = (const float*)d_in[4];
    const float* epsp     = (const float*)d_in[5];
    const float* epsr     = (const float*)d_in[6];
    float* out = (float*)d_out;

    char* ws = (char*)d_ws;
    size_t off = 0;
    auto alloc = [&](size_t bytes) {
        off = (off + 255) & ~(size_t)255;
        size_t o = off; off += bytes; return o;
    };
    float2* field  = (float2*)(ws + alloc((size_t)NN * NN * 8));
    float*  kgamma = (float*) (ws + alloc((size_t)NN * NN * 4));
    float2* tw     = (float2*)(ws + alloc((size_t)NN * 8));
    float2* R1     = (float2*)(ws + alloc((size_t)NN * NN * 8));
    float2* Ef     = (float2*)(ws + alloc((size_t)NN * NN * 8));
    float2* part   = (float2*)(ws + alloc((size_t)NE * PW * NN * 8));
    float*  psf    = (float*) (ws + alloc((size_t)NE * PW * PW * 4));
    float*  scales = (float*) (ws + alloc((size_t)NE * 4));
    float*  kern   = (float*) (ws + alloc((size_t)64 * 4));
    float*  canvas = (float*) (ws + alloc((size_t)BATCH * CAN * CAN * 4));
    (void)ws_size; (void)n_in; (void)in_sizes; (void)out_size;

    k_init<<<dim3((NN * NN + 255) / 256), 256, 0, stream>>>(phase, field, kgamma, tw);
    k_zero<<<(BATCH * CAN * CAN + 255) / 256, 256, 0, stream>>>(canvas, BATCH * CAN * CAN);
    // fft2: rows then cols (forward, sign=-1)
    k_dft500<<<NN, 256, 0, stream>>>(field, R1, tw, NN, 1, NN, 1, -1.0f);
    k_dft500<<<NN, 256, 0, stream>>>(R1, Ef, tw, 1, NN, 1, NN, -1.0f);
    // partial inverse transforms for the 31x31 crop, all 64 z-planes
    k_prop_rows<<<dim3(NN, 2), 256, 0, stream>>>(Ef, kgamma, zs, part);
    k_prop_cols<<<dim3(PW, NE), 256, 0, stream>>>(part, psf);
    k_norm<<<NE, 256, 0, stream>>>(psf, scales);
    k_kern<<<1, 64, 0, stream>>>(std_u, kern);
    k_scatter<<<dim3(NE, BATCH), 256, 0, stream>>>(psf, scales, xyz, canvas);
    k_final<<<(BATCH * OHW * OHW + 255) / 256, 256, 0, stream>>>(canvas, kern, epsd, epsp, epsr, out);
}

// Round 4
// 288.289 us; speedup vs baseline: 1.0910x; 1.0910x over previous
//
#include <hip/hip_runtime.h>
#include <math.h>

#define NN 500
#define NE 64
#define BATCH 8
#define RR 15
#define PW 31            // 2R+1
#define CAN 200
#define OHW 198
#define TWO_PI_F 6.28318530717958647692f

// ---------------------------------------------------------------------------
// K0: build pupil field, K*GAMMA table, and 500-pt twiddle table
// ---------------------------------------------------------------------------
__global__ void k_init(const float* __restrict__ phase,
                       float2* __restrict__ field,
                       float* __restrict__ kgamma,
                       float2* __restrict__ tw) {
    int idx = blockIdx.x * blockDim.x + threadIdx.x;
    if (idx < NN) {
        double th = 2.0 * M_PI * (double)idx / (double)NN;
        tw[idx] = make_float2((float)cos(th), (float)sin(th));
    }
    if (idx >= NN * NN) return;
    int i = idx / NN, j = idx % NN;

    double x = (double)(j - 250) * 1e-6;
    double y = (double)(i - 250) * 1e-6;
    double r2 = x * x + y * y;
    double inc_d = exp(-r2 / (2.0 * 1.5e-4 * 1.5e-4));
    double c1 = fmod(M_PI / (5.32e-7 * 0.1) * r2, 2.0 * M_PI);
    float inc = (float)inc_d;
    float b1r = (float)cos(c1);
    float b1i = (float)(-sin(c1));
    float ph = phase[idx];
    float sp, cp;
    sincosf(ph, &sp, &cp);
    float ar = inc * cp, ai = inc * sp;
    field[idx] = make_float2(ar * b1r - ai * b1i, ar * b1i + ai * b1r);

    double fy = (double)((i < 250) ? i : i - 500) * 2000.0;
    double fx = (double)((j < 250) ? j : j - 500) * 2000.0;
    double a = 5.32e-7 * fx;
    double b = 5.32e-7 * fy;
    double g = 1.0 - a * a - b * b;
    g = (g > 0.0) ? sqrt(g) : 0.0;
    float Kf = (float)(2.0 * M_PI * 1.0 / 5.32e-7);
    kgamma[idx] = Kf * (float)g;
}

// ---------------------------------------------------------------------------
// Full 500-pt DFT along one axis, pair trick (k and k+250 share a rotator via
// (-1)^n), rotation recurrence with exact-table resync every 64 n.
// ---------------------------------------------------------------------------
__global__ void k_dft500(const float2* __restrict__ src, float2* __restrict__ dst,
                         const float2* __restrict__ tw,
                         int src_line, int src_elem, int dst_line, int dst_elem,
                         float sgn) {
    __shared__ __align__(16) float2 xs[NN];
    __shared__ float2 tts[NN];
    int line = blockIdx.x;
    const float2* s = src + (size_t)line * src_line;
    for (int n = threadIdx.x; n < NN; n += blockDim.x) {
        xs[n] = s[(size_t)n * src_elem];
        float2 t = tw[n];
        tts[n] = make_float2(t.x, sgn * t.y);
    }
    __syncthreads();
    int k = threadIdx.x;
    if (k < 250) {
        float2 s1 = tts[k];
        float wr = 1.f, wi = 0.f;
        float a1r = 0.f, a1i = 0.f, a2r = 0.f, a2i = 0.f;
        for (int n = 0; n < NN; n += 2) {
            if ((n & 63) == 0) {   // resync rotator from exact table
                int idx = (n * k) % NN;
                float2 e = tts[idx];
                wr = e.x; wi = e.y;
            }
            float4 xy = *(const float4*)&xs[n];   // xs[n], xs[n+1]
            float tr = wr * s1.x - wi * s1.y;     // twiddle at n+1
            float ti = wr * s1.y + wi * s1.x;
            float pr = xy.x * wr - xy.y * wi;
            float pi = xy.x * wi + xy.y * wr;
            float qr = xy.z * tr - xy.w * ti;
            float qi = xy.z * ti + xy.w * tr;
            a1r += pr + qr;  a1i += pi + qi;
            a2r += pr - qr;  a2i += pi - qi;      // output k+250: *(-1)^n
            wr = tr * s1.x - ti * s1.y;           // advance to n+2
            wi = tr * s1.y + ti * s1.x;
        }
        float2* d = dst + (size_t)line * dst_line;
        d[(size_t)k * dst_elem] = make_float2(a1r, a1i);
        d[(size_t)(k + 250) * dst_elem] = make_float2(a2r, a2i);
    }
}

// ---------------------------------------------------------------------------
// B1 v4: block = (u, zhalf), 4 passes of 8 resident z-planes.
// Thread = (zg in [0,2), co in [0,16), vs in [0,8)): tile Tz=4 z x Tc=2 c,
// v split 8 ways INTRA-WAVE (vs = lane&7 -> 3 shfl_xor levels, no LDS red).
// Data reads are ds_read_b128 (2 consecutive v per read): 4 reads -> 64 FMA.
//   part[z][c][u] = sum_v Ef[u,v]*e^{i*kg[u,v]*z} * e^{+2pi*i*v*c/500}
// ---------------------------------------------------------------------------
__global__ void __launch_bounds__(256, 4)
k_prop_rows(const float2* __restrict__ Ef,
            const float* __restrict__ kgamma,
            const float* __restrict__ zs,
            float2* __restrict__ part) {
    __shared__ __align__(16) float2 Ys[8][NN];   // 32000 B
    __shared__ float2 efs[NN];                   // 4000 B
    __shared__ float  kgs[NN];                   // 2000 B
    int u = blockIdx.x;
    int zhalf = blockIdx.y;
    int t = threadIdx.x;
    int zg = t >> 7;            // 0..1 : which 4-z half of the resident 8
    int co = (t >> 3) & 15;     // 0..15 : c-pair index
    int vs = t & 7;             // 0..7 : v-segment (lane bits 0..2)

    const float2* erow = Ef + (size_t)u * NN;
    const float* grow = kgamma + (size_t)u * NN;
    for (int v = t; v < NN; v += 256) {
        efs[v] = erow[v];
        kgs[v] = grow[v];
    }

    // two c-values per thread: c0 odd-offsets 235..265, c1 = c0+1 (co=15 -> dummy)
    int c0 = 235 + 2 * co;
    // rotator state per c: w = e^{+2pi i * v * c / 500} at v = 2*vs (pair start),
    // s1 = e^{+2pi i * c / 500} (v -> v+1), step = e^{+2pi i * 16*c/500} (pair += 8)
    float w0r[2], w0i[2], s1r[2], s1i[2], str[2], sti[2];
#pragma unroll
    for (int cl = 0; cl < 2; ++cl) {
        int c = c0 + cl;
        float th0 = (TWO_PI_F / NN) * (float)((2 * vs * c) % NN);
        sincosf(th0, &w0i[cl], &w0r[cl]);
        float th1 = (TWO_PI_F / NN) * (float)(c % NN);
        sincosf(th1, &s1i[cl], &s1r[cl]);
        float ths = (TWO_PI_F / NN) * (float)((16 * c) % NN);
        sincosf(ths, &sti[cl], &str[cl]);
    }
    __syncthreads();

    for (int g = 0; g < 4; ++g) {
        int zbase = zhalf * 32 + g * 8;
        float zv[8];
#pragma unroll
        for (int zi = 0; zi < 8; ++zi) zv[zi] = zs[zbase + zi];
        // modulate: Ys[zi][v] = efs[v] * e^{i*kgs[v]*z}
        for (int v = t; v < NN; v += 256) {
            float2 e = efs[v];
            float kg = kgs[v];
#pragma unroll
            for (int zi = 0; zi < 8; ++zi) {
                float s, cc;
                sincosf(kg * zv[zi], &s, &cc);
                Ys[zi][v] = make_float2(e.x * cc - e.y * s, e.x * s + e.y * cc);
            }
        }
        __syncthreads();

        // partial DFT: acc[cl][j] over z = zg*4 + j, c = c0+cl
        float wr[2], wi[2];
#pragma unroll
        for (int cl = 0; cl < 2; ++cl) { wr[cl] = w0r[cl]; wi[cl] = w0i[cl]; }
        float accr[2][4], acci[2][4];
#pragma unroll
        for (int cl = 0; cl < 2; ++cl)
#pragma unroll
            for (int j = 0; j < 4; ++j) { accr[cl][j] = 0.f; acci[cl][j] = 0.f; }

        for (int p = vs; p < 250; p += 8) {      // v = 2p, 2p+1
            int v = 2 * p;
            float4 xv[4];
#pragma unroll
            for (int j = 0; j < 4; ++j)
                xv[j] = *(const float4*)&Ys[zg * 4 + j][v];
#pragma unroll
            for (int cl = 0; cl < 2; ++cl) {
                float ar = wr[cl], ai = wi[cl];              // twiddle at v
                float br = ar * s1r[cl] - ai * s1i[cl];      // twiddle at v+1
                float bi = ar * s1i[cl] + ai * s1r[cl];
#pragma unroll
                for (int j = 0; j < 4; ++j) {
                    float4 x = xv[j];
                    accr[cl][j] += x.x * ar - x.y * ai;
                    acci[cl][j] += x.x * ai + x.y * ar;
                    accr[cl][j] += x.z * br - x.w * bi;
                    acci[cl][j] += x.z * bi + x.w * br;
                }
                wr[cl] = ar * str[cl] - ai * sti[cl];        // advance pair
                wi[cl] = ar * sti[cl] + ai * str[cl];
            }
        }

        // reduce over vs (lane bits 0..2): 3 levels, 16 floats
#pragma unroll
        for (int cl = 0; cl < 2; ++cl)
#pragma unroll
            for (int j = 0; j < 4; ++j) {
#pragma unroll
                for (int m = 1; m < 8; m <<= 1) {
                    accr[cl][j] += __shfl_xor(accr[cl][j], m);
                    acci[cl][j] += __shfl_xor(acci[cl][j], m);
                }
            }
        if (vs == 0) {
#pragma unroll
            for (int cl = 0; cl < 2; ++cl) {
                int c = c0 + cl;
                if (c <= 265) {
#pragma unroll
                    for (int j = 0; j < 4; ++j) {
                        int z = zbase + zg * 4 + j;
                        part[((size_t)z * PW + (c - 235)) * NN + u] =
                            make_float2(accr[cl][j], acci[cl][j]);
                    }
                }
            }
        }
        __syncthreads();
    }
}

// ---------------------------------------------------------------------------
// B2: per (z,c): Eprop[r,c] = (1/500^2) * sum_u part[z][c][u]*e^{+2pi*i*u*r/500}
// ---------------------------------------------------------------------------
__global__ void k_prop_cols(const float2* __restrict__ part,
                            float* __restrict__ psf) {
    __shared__ float2 X[NN];
    int ci = blockIdx.x;   // 31
    int z = blockIdx.y;    // 64
    int t = threadIdx.x;
    const float2* col = part + ((size_t)z * PW + ci) * NN;
    for (int u = t; u < NN; u += 256) X[u] = col[u];
    __syncthreads();
    if (t < PW * 8) {
        int ri = t >> 3, seg = t & 7;
        int r = 235 + ri;
        float wr, wi, sr, si;
        {
            float th0 = (TWO_PI_F / NN) * (float)((seg * r) % NN);
            sincosf(th0, &wi, &wr);
            float ths = (TWO_PI_F / NN) * (float)((8 * r) % NN);
            sincosf(ths, &si, &sr);
        }
        float ar = 0.f, ai = 0.f;
        for (int u = seg; u < NN; u += 8) {
            float2 xv = X[u];
            ar += xv.x * wr - xv.y * wi;
            ai += xv.x * wi + xv.y * wr;
            float nwr = wr * sr - wi * si;
            wi = wr * si + wi * sr;
            wr = nwr;
        }
#pragma unroll
        for (int m = 1; m < 8; m <<= 1) {
            ar += __shfl_xor(ar, m);
            ai += __shfl_xor(ai, m);
        }
        if (seg == 0 && ri < PW) {
            const float inv = 1.0f / 250000.0f;
            float re = ar * inv, im = ai * inv;
            psf[(size_t)z * (PW * PW) + ri * PW + ci] = re * re + im * im;
        }
    }
}

// ---------------------------------------------------------------------------
__global__ void k_norm(const float* __restrict__ psf, float* __restrict__ scales) {
    __shared__ float red[256];
    int z = blockIdx.x;
    float s = 0.f;
    for (int p = threadIdx.x; p < PW * PW; p += 256) s += psf[z * PW * PW + p];
    red[threadIdx.x] = s;
    __syncthreads();
    for (int o = 128; o > 0; o >>= 1) {
        if (threadIdx.x < o) red[threadIdx.x] += red[threadIdx.x + o];
        __syncthreads();
    }
    if (threadIdx.x == 0) scales[z] = 1.0e6f / (red[0] + 1e-12f);
}

__global__ void k_kern(const float* __restrict__ std_u, float* __restrict__ kern) {
    int t = threadIdx.x;
    if (t < 49) {
        float stdv = 0.8f + 0.4f * std_u[0];
        float s2 = stdv * stdv;
        int a = t / 7 - 3, b = t % 7 - 3;
        float g = (float)exp(-0.5 * (double)(a * a + b * b));
        kern[t] = (1.0f / (2.0f * (float)M_PI * s2)) * powf(g, 1.0f / s2);
    }
}

__global__ void k_zero(float* __restrict__ p, int n) {
    int i = blockIdx.x * blockDim.x + threadIdx.x;
    if (i < n) p[i] = 0.f;
}

__global__ void k_scatter(const float* __restrict__ psf,
                          const float* __restrict__ scales,
                          const int* __restrict__ xyz,
                          float* __restrict__ canvas) {
    int e = blockIdx.x;
    int b = blockIdx.y;
    int r0 = xyz[(b * NE + e) * 2 + 0] - RR;
    int c0 = xyz[(b * NE + e) * 2 + 1] - RR;
    float sc = scales[e];
    float* cb = canvas + (size_t)b * (CAN * CAN);
    for (int p = threadIdx.x; p < PW * PW; p += blockDim.x) {
        int i = p / PW, j = p % PW;
        atomicAdd(cb + (r0 + i) * CAN + (c0 + j), psf[e * PW * PW + p] * sc);
    }
}

__global__ void k_final(const float* __restrict__ canvas,
                        const float* __restrict__ kern,
                        const float* __restrict__ eps_dark,
                        const float* __restrict__ eps_photon,
                        const float* __restrict__ eps_read,
                        float* __restrict__ out) {
    __shared__ float kk[49];
    if (threadIdx.x < 49) kk[threadIdx.x] = kern[threadIdx.x];
    __syncthreads();
    int idx = blockIdx.x * blockDim.x + threadIdx.x;
    if (idx >= BATCH * OHW * OHW) return;
    int b = idx / (OHW * OHW);
    int rem = idx % (OHW * OHW);
    int i = rem / OHW, j = rem % OHW;
    const float* cb = canvas + (size_t)b * (CAN * CAN);
    float acc = 0.f;
#pragma unroll
    for (int a = 0; a < 7; ++a) {
        int r = i + a - 2;
        if (r < 0 || r >= CAN) continue;
#pragma unroll
        for (int q = 0; q < 7; ++q) {
            int c = j + q - 2;
            if (c < 0 || c >= CAN) continue;
            acc += cb[r * CAN + c] * kk[a * 7 + q];
        }
    }
    float sig = acc * 0.9f;
    float dark = 0.005f + eps_dark[idx] * sqrtf(0.005f);
    float total = fmaxf(sig + dark, 0.0f);
    float noisy = total + eps_photon[idx] * sqrtf(fmaxf(total, 1e-12f));
    float elec = noisy + eps_read[idx] * 1.6f;
    float adu = fminf(fmaxf(elec * 2.0f, 0.0f), 65535.0f);
    float v = (adu <= 10.0f) ? 1.0f : fminf(adu, 4.0e9f);
    out[idx] = v / 4.0e9f;
}

// ---------------------------------------------------------------------------
extern "C" void kernel_launch(void* const* d_in, const int* in_sizes, int n_in,
                              void* d_out, int out_size, void* d_ws, size_t ws_size,
                              hipStream_t stream) {
    const float* phase    = (const float*)d_in[0];
    const float* zs       = (const float*)d_in[1];
    const int*   xyz      = (const int*)d_in[2];
    const float* std_u    = (const float*)d_in[3];
    const float* epsd     = (const float*)d_in[4];
    const float* epsp     = (const float*)d_in[5];
    const float* epsr     = (const float*)d_in[6];
    float* out = (float*)d_out;

    char* ws = (char*)d_ws;
    size_t off = 0;
    auto alloc = [&](size_t bytes) {
        off = (off + 255) & ~(size_t)255;
        size_t o = off; off += bytes; return o;
    };
    float2* field  = (float2*)(ws + alloc((size_t)NN * NN * 8));
    float*  kgamma = (float*) (ws + alloc((size_t)NN * NN * 4));
    float2* tw     = (float2*)(ws + alloc((size_t)NN * 8));
    float2* R1     = (float2*)(ws + alloc((size_t)NN * NN * 8));
    float2* Ef     = (float2*)(ws + alloc((size_t)NN * NN * 8));
    float2* part   = (float2*)(ws + alloc((size_t)NE * PW * NN * 8));
    float*  psf    = (float*) (ws + alloc((size_t)NE * PW * PW * 4));
    float*  scales = (float*) (ws + alloc((size_t)NE * 4));
    float*  kern   = (float*) (ws + alloc((size_t)64 * 4));
    float*  canvas = (float*) (ws + alloc((size_t)BATCH * CAN * CAN * 4));
    (void)ws_size; (void)n_in; (void)in_sizes; (void)out_size;

    k_init<<<dim3((NN * NN + 255) / 256), 256, 0, stream>>>(phase, field, kgamma, tw);
    k_zero<<<(BATCH * CAN * CAN + 255) / 256, 256, 0, stream>>>(canvas, BATCH * CAN * CAN);
    // fft2: rows then cols (forward, sign=-1)
    k_dft500<<<NN, 256, 0, stream>>>(field, R1, tw, NN, 1, NN, 1, -1.0f);
    k_dft500<<<NN, 256, 0, stream>>>(R1, Ef, tw, 1, NN, 1, NN, -1.0f);
    // partial inverse transforms for the 31x31 crop, all 64 z-planes
    k_prop_rows<<<dim3(NN, 2), 256, 0, stream>>>(Ef, kgamma, zs, part);
    k_prop_cols<<<dim3(PW, NE), 256, 0, stream>>>(part, psf);
    k_norm<<<NE, 256, 0, stream>>>(psf, scales);
    k_kern<<<1, 64, 0, stream>>>(std_u, kern);
    k_scatter<<<dim3(NE, BATCH), 256, 0, stream>>>(psf, scales, xyz, canvas);
    k_final<<<(BATCH * OHW * OHW + 255) / 256, 256, 0, stream>>>(canvas, kern, epsd, epsp, epsr, out);
}

// Round 5
// 259.772 us; speedup vs baseline: 1.2108x; 1.1098x over previous
//
#include <hip/hip_runtime.h>
#include <math.h>

#define NN 500
#define NE 64
#define BATCH 8
#define RR 15
#define PW 31            // 2R+1
#define CAN 200
#define OHW 198
#define TWO_PI_F 6.28318530717958647692f

// ---------------------------------------------------------------------------
// K0: build pupil field, K*GAMMA table, and 500-pt twiddle table
// ---------------------------------------------------------------------------
__global__ void k_init(const float* __restrict__ phase,
                       float2* __restrict__ field,
                       float* __restrict__ kgamma,
                       float2* __restrict__ tw) {
    int idx = blockIdx.x * blockDim.x + threadIdx.x;
    if (idx < NN) {
        double th = 2.0 * M_PI * (double)idx / (double)NN;
        tw[idx] = make_float2((float)cos(th), (float)sin(th));
    }
    if (idx >= NN * NN) return;
    int i = idx / NN, j = idx % NN;

    double x = (double)(j - 250) * 1e-6;
    double y = (double)(i - 250) * 1e-6;
    double r2 = x * x + y * y;
    double inc_d = exp(-r2 / (2.0 * 1.5e-4 * 1.5e-4));
    double c1 = fmod(M_PI / (5.32e-7 * 0.1) * r2, 2.0 * M_PI);
    float inc = (float)inc_d;
    float b1r = (float)cos(c1);
    float b1i = (float)(-sin(c1));
    float ph = phase[idx];
    float sp, cp;
    sincosf(ph, &sp, &cp);
    float ar = inc * cp, ai = inc * sp;
    field[idx] = make_float2(ar * b1r - ai * b1i, ar * b1i + ai * b1r);

    double fy = (double)((i < 250) ? i : i - 500) * 2000.0;
    double fx = (double)((j < 250) ? j : j - 500) * 2000.0;
    double a = 5.32e-7 * fx;
    double b = 5.32e-7 * fy;
    double g = 1.0 - a * a - b * b;
    g = (g > 0.0) ? sqrt(g) : 0.0;
    float Kf = (float)(2.0 * M_PI * 1.0 / 5.32e-7);
    kgamma[idx] = Kf * (float)g;
}

// ---------------------------------------------------------------------------
// Full 500-pt DFT along one axis, pair trick (k and k+250 share a rotator via
// (-1)^n), rotation recurrence with exact-table resync every 64 n.
// ---------------------------------------------------------------------------
__global__ void k_dft500(const float2* __restrict__ src, float2* __restrict__ dst,
                         const float2* __restrict__ tw,
                         int src_line, int src_elem, int dst_line, int dst_elem,
                         float sgn) {
    __shared__ __align__(16) float2 xs[NN];
    __shared__ float2 tts[NN];
    int line = blockIdx.x;
    const float2* s = src + (size_t)line * src_line;
    for (int n = threadIdx.x; n < NN; n += blockDim.x) {
        xs[n] = s[(size_t)n * src_elem];
        float2 t = tw[n];
        tts[n] = make_float2(t.x, sgn * t.y);
    }
    __syncthreads();
    int k = threadIdx.x;
    if (k < 250) {
        float2 s1 = tts[k];
        float wr = 1.f, wi = 0.f;
        float a1r = 0.f, a1i = 0.f, a2r = 0.f, a2i = 0.f;
        for (int n = 0; n < NN; n += 2) {
            if ((n & 63) == 0) {   // resync rotator from exact table
                int idx = (n * k) % NN;
                float2 e = tts[idx];
                wr = e.x; wi = e.y;
            }
            float4 xy = *(const float4*)&xs[n];   // xs[n], xs[n+1]
            float tr = wr * s1.x - wi * s1.y;     // twiddle at n+1
            float ti = wr * s1.y + wi * s1.x;
            float pr = xy.x * wr - xy.y * wi;
            float pi = xy.x * wi + xy.y * wr;
            float qr = xy.z * tr - xy.w * ti;
            float qi = xy.z * ti + xy.w * tr;
            a1r += pr + qr;  a1i += pi + qi;
            a2r += pr - qr;  a2i += pi - qi;      // output k+250: *(-1)^n
            wr = tr * s1.x - ti * s1.y;           // advance to n+2
            wi = tr * s1.y + ti * s1.x;
        }
        float2* d = dst + (size_t)line * dst_line;
        d[(size_t)k * dst_elem] = make_float2(a1r, a1i);
        d[(size_t)(k + 250) * dst_elem] = make_float2(a2r, a2i);
    }
}

// ---------------------------------------------------------------------------
// B1 v5: block = (u, zhalf), 4 passes of 8 resident z-planes. LDS = Ys only
// (Ef/kgamma rows re-read from global, L2-resident).
// Wave w handles z rows {2w, 2w+1}. Lane = (co in [0,8), vs in [0,8)):
// Tc=4 c-values per thread, v-dim split 8 ways intra-wave (3 shfl levels).
// Parity fold: e^{2pi i (v+250)c/500} = (-1)^c e^{2pi i v c/500}, so
//   sum_v Y[v] w^vc = sum_{v<250} (Y[v] +- Y[v+250]) w^vc
// with the +- sums shared across all c (c0 = 235+4co is odd, so parity of
// c = c0+cl is !(cl&1) at compile time per cl).
//   part[z][c][u] = sum_v Ef[u,v]*e^{i*kg[u,v]*z} * e^{+2pi*i*v*c/500}
// ---------------------------------------------------------------------------
__global__ void __launch_bounds__(256, 5)
k_prop_rows(const float2* __restrict__ Ef,
            const float* __restrict__ kgamma,
            const float* __restrict__ zs,
            float2* __restrict__ part) {
    __shared__ __align__(16) float2 Ys[8][NN];   // 32000 B (only LDS)
    int u = blockIdx.x;
    int zhalf = blockIdx.y;
    int t = threadIdx.x;
    int w = t >> 6;             // wave id 0..3 -> z rows 2w, 2w+1
    int lane = t & 63;
    int co = lane >> 3;         // 0..7 : c-quad index (bits 3..5)
    int vs = lane & 7;          // 0..7 : v-segment (bits 0..2)
    int c0 = 235 + 4 * co;      // c = c0..c0+3 (co=7,cl=3 -> 266 dummy)

    const float2* erow = Ef + (size_t)u * NN;
    const float* grow = kgamma + (size_t)u * NN;

    // rotators per cl: w0 = e^{+2pi i (2 vs c)/500} (column v=2vs),
    // s1 = e^{+2pi i c/500} (v -> v+1), st = e^{+2pi i 16c/500} (pair-col += 8)
    float w0r[4], w0i[4], s1r[4], s1i[4], str[4], sti[4];
#pragma unroll
    for (int cl = 0; cl < 4; ++cl) {
        int c = c0 + cl;
        float th0 = (TWO_PI_F / NN) * (float)((2 * vs * c) % NN);
        sincosf(th0, &w0i[cl], &w0r[cl]);
        float th1 = (TWO_PI_F / NN) * (float)(c % NN);
        sincosf(th1, &s1i[cl], &s1r[cl]);
        float ths = (TWO_PI_F / NN) * (float)((16 * c) % NN);
        sincosf(ths, &sti[cl], &str[cl]);
    }

    for (int g = 0; g < 4; ++g) {
        int zbase = zhalf * 32 + g * 8;
        float zv[8];
#pragma unroll
        for (int zi = 0; zi < 8; ++zi) zv[zi] = zs[zbase + zi];
        // modulate: Ys[zi][v] = Ef[u,v] * e^{i*kg[u,v]*z}
        for (int v = t; v < NN; v += 256) {
            float2 e = erow[v];
            float kg = grow[v];
#pragma unroll
            for (int zi = 0; zi < 8; ++zi) {
                float s, cc;
                sincosf(kg * zv[zi], &s, &cc);
                Ys[zi][v] = make_float2(e.x * cc - e.y * s, e.x * s + e.y * cc);
            }
        }
        __syncthreads();

        // partial DFT with parity fold: acc[cl][j], j = z row 2w+j
        float wr[4], wi[4];
#pragma unroll
        for (int cl = 0; cl < 4; ++cl) { wr[cl] = w0r[cl]; wi[cl] = w0i[cl]; }
        float accr[4][2], acci[4][2];
#pragma unroll
        for (int cl = 0; cl < 4; ++cl)
#pragma unroll
            for (int j = 0; j < 2; ++j) { accr[cl][j] = 0.f; acci[cl][j] = 0.f; }

        for (int pc = vs; pc < 125; pc += 8) {   // pair-columns: v=2pc, 2pc+1
            int v = 2 * pc;
            float4 x0a = *(const float4*)&Ys[2 * w + 0][v];        // z0: v, v+1
            float4 x0b = *(const float4*)&Ys[2 * w + 0][v + 250];  // z0: v+250, v+251
            float4 x1a = *(const float4*)&Ys[2 * w + 1][v];        // z1
            float4 x1b = *(const float4*)&Ys[2 * w + 1][v + 250];
            // parity sums: e = a+b (even c), o = a-b (odd c); per z, per column
            float e0vr = x0a.x + x0b.x, e0vi = x0a.y + x0b.y;
            float o0vr = x0a.x - x0b.x, o0vi = x0a.y - x0b.y;
            float e0wr_ = x0a.z + x0b.z, e0wi_ = x0a.w + x0b.w;
            float o0wr_ = x0a.z - x0b.z, o0wi_ = x0a.w - x0b.w;
            float e1vr = x1a.x + x1b.x, e1vi = x1a.y + x1b.y;
            float o1vr = x1a.x - x1b.x, o1vi = x1a.y - x1b.y;
            float e1wr_ = x1a.z + x1b.z, e1wi_ = x1a.w + x1b.w;
            float o1wr_ = x1a.z - x1b.z, o1wi_ = x1a.w - x1b.w;
#pragma unroll
            for (int cl = 0; cl < 4; ++cl) {
                float ar = wr[cl], ai = wi[cl];              // twiddle at v
                float br = ar * s1r[cl] - ai * s1i[cl];      // twiddle at v+1
                float bi = ar * s1i[cl] + ai * s1r[cl];
                // c = c0+cl, c0 odd: cl even -> c odd (use o), cl odd -> c even (use e)
                if ((cl & 1) == 0) {
                    accr[cl][0] += o0vr * ar - o0vi * ai + o0wr_ * br - o0wi_ * bi;
                    acci[cl][0] += o0vr * ai + o0vi * ar + o0wr_ * bi + o0wi_ * br;
                    accr[cl][1] += o1vr * ar - o1vi * ai + o1wr_ * br - o1wi_ * bi;
                    acci[cl][1] += o1vr * ai + o1vi * ar + o1wr_ * bi + o1wi_ * br;
                } else {
                    accr[cl][0] += e0vr * ar - e0vi * ai + e0wr_ * br - e0wi_ * bi;
                    acci[cl][0] += e0vr * ai + e0vi * ar + e0wr_ * bi + e0wi_ * br;
                    accr[cl][1] += e1vr * ar - e1vi * ai + e1wr_ * br - e1wi_ * bi;
                    acci[cl][1] += e1vr * ai + e1vi * ar + e1wr_ * bi + e1wi_ * br;
                }
                float nwr = ar * str[cl] - ai * sti[cl];     // advance pair-col
                wi[cl] = ar * sti[cl] + ai * str[cl];
                wr[cl] = nwr;
            }
        }

        // reduce over vs (lane bits 0..2)
#pragma unroll
        for (int cl = 0; cl < 4; ++cl)
#pragma unroll
            for (int j = 0; j < 2; ++j) {
#pragma unroll
                for (int m = 1; m < 8; m <<= 1) {
                    accr[cl][j] += __shfl_xor(accr[cl][j], m);
                    acci[cl][j] += __shfl_xor(acci[cl][j], m);
                }
            }
        if (vs == 0) {
#pragma unroll
            for (int cl = 0; cl < 4; ++cl) {
                int c = c0 + cl;
                if (c <= 265) {
#pragma unroll
                    for (int j = 0; j < 2; ++j) {
                        int z = zbase + 2 * w + j;
                        part[((size_t)z * PW + (c - 235)) * NN + u] =
                            make_float2(accr[cl][j], acci[cl][j]);
                    }
                }
            }
        }
        __syncthreads();
    }
}

// ---------------------------------------------------------------------------
// B2: per (z,c): Eprop[r,c] = (1/500^2) * sum_u part[z][c][u]*e^{+2pi*i*u*r/500}
// ---------------------------------------------------------------------------
__global__ void k_prop_cols(const float2* __restrict__ part,
                            float* __restrict__ psf) {
    __shared__ float2 X[NN];
    int ci = blockIdx.x;   // 31
    int z = blockIdx.y;    // 64
    int t = threadIdx.x;
    const float2* col = part + ((size_t)z * PW + ci) * NN;
    for (int u = t; u < NN; u += 256) X[u] = col[u];
    __syncthreads();
    if (t < PW * 8) {
        int ri = t >> 3, seg = t & 7;
        int r = 235 + ri;
        float wr, wi, sr, si;
        {
            float th0 = (TWO_PI_F / NN) * (float)((seg * r) % NN);
            sincosf(th0, &wi, &wr);
            float ths = (TWO_PI_F / NN) * (float)((8 * r) % NN);
            sincosf(ths, &si, &sr);
        }
        float ar = 0.f, ai = 0.f;
        for (int u = seg; u < NN; u += 8) {
            float2 xv = X[u];
            ar += xv.x * wr - xv.y * wi;
            ai += xv.x * wi + xv.y * wr;
            float nwr = wr * sr - wi * si;
            wi = wr * si + wi * sr;
            wr = nwr;
        }
#pragma unroll
        for (int m = 1; m < 8; m <<= 1) {
            ar += __shfl_xor(ar, m);
            ai += __shfl_xor(ai, m);
        }
        if (seg == 0 && ri < PW) {
            const float inv = 1.0f / 250000.0f;
            float re = ar * inv, im = ai * inv;
            psf[(size_t)z * (PW * PW) + ri * PW + ci] = re * re + im * im;
        }
    }
}

// ---------------------------------------------------------------------------
__global__ void k_norm(const float* __restrict__ psf, float* __restrict__ scales) {
    __shared__ float red[256];
    int z = blockIdx.x;
    float s = 0.f;
    for (int p = threadIdx.x; p < PW * PW; p += 256) s += psf[z * PW * PW + p];
    red[threadIdx.x] = s;
    __syncthreads();
    for (int o = 128; o > 0; o >>= 1) {
        if (threadIdx.x < o) red[threadIdx.x] += red[threadIdx.x + o];
        __syncthreads();
    }
    if (threadIdx.x == 0) scales[z] = 1.0e6f / (red[0] + 1e-12f);
}

__global__ void k_kern(const float* __restrict__ std_u, float* __restrict__ kern) {
    int t = threadIdx.x;
    if (t < 49) {
        float stdv = 0.8f + 0.4f * std_u[0];
        float s2 = stdv * stdv;
        int a = t / 7 - 3, b = t % 7 - 3;
        float g = (float)exp(-0.5 * (double)(a * a + b * b));
        kern[t] = (1.0f / (2.0f * (float)M_PI * s2)) * powf(g, 1.0f / s2);
    }
}

__global__ void k_zero(float* __restrict__ p, int n) {
    int i = blockIdx.x * blockDim.x + threadIdx.x;
    if (i < n) p[i] = 0.f;
}

__global__ void k_scatter(const float* __restrict__ psf,
                          const float* __restrict__ scales,
                          const int* __restrict__ xyz,
                          float* __restrict__ canvas) {
    int e = blockIdx.x;
    int b = blockIdx.y;
    int r0 = xyz[(b * NE + e) * 2 + 0] - RR;
    int c0 = xyz[(b * NE + e) * 2 + 1] - RR;
    float sc = scales[e];
    float* cb = canvas + (size_t)b * (CAN * CAN);
    for (int p = threadIdx.x; p < PW * PW; p += blockDim.x) {
        int i = p / PW, j = p % PW;
        atomicAdd(cb + (r0 + i) * CAN + (c0 + j), psf[e * PW * PW + p] * sc);
    }
}

__global__ void k_final(const float* __restrict__ canvas,
                        const float* __restrict__ kern,
                        const float* __restrict__ eps_dark,
                        const float* __restrict__ eps_photon,
                        const float* __restrict__ eps_read,
                        float* __restrict__ out) {
    __shared__ float kk[49];
    if (threadIdx.x < 49) kk[threadIdx.x] = kern[threadIdx.x];
    __syncthreads();
    int idx = blockIdx.x * blockDim.x + threadIdx.x;
    if (idx >= BATCH * OHW * OHW) return;
    int b = idx / (OHW * OHW);
    int rem = idx % (OHW * OHW);
    int i = rem / OHW, j = rem % OHW;
    const float* cb = canvas + (size_t)b * (CAN * CAN);
    float acc = 0.f;
#pragma unroll
    for (int a = 0; a < 7; ++a) {
        int r = i + a - 2;
        if (r < 0 || r >= CAN) continue;
#pragma unroll
        for (int q = 0; q < 7; ++q) {
            int c = j + q - 2;
            if (c < 0 || c >= CAN) continue;
            acc += cb[r * CAN + c] * kk[a * 7 + q];
        }
    }
    float sig = acc * 0.9f;
    float dark = 0.005f + eps_dark[idx] * sqrtf(0.005f);
    float total = fmaxf(sig + dark, 0.0f);
    float noisy = total + eps_photon[idx] * sqrtf(fmaxf(total, 1e-12f));
    float elec = noisy + eps_read[idx] * 1.6f;
    float adu = fminf(fmaxf(elec * 2.0f, 0.0f), 65535.0f);
    float v = (adu <= 10.0f) ? 1.0f : fminf(adu, 4.0e9f);
    out[idx] = v / 4.0e9f;
}

// ---------------------------------------------------------------------------
extern "C" void kernel_launch(void* const* d_in, const int* in_sizes, int n_in,
                              void* d_out, int out_size, void* d_ws, size_t ws_size,
                              hipStream_t stream) {
    const float* phase    = (const float*)d_in[0];
    const float* zs       = (const float*)d_in[1];
    const int*   xyz      = (const int*)d_in[2];
    const float* std_u    = (const float*)d_in[3];
    const float* epsd     = (const float*)d_in[4];
    const float* epsp     = (const float*)d_in[5];
    const float* epsr     = (const float*)d_in[6];
    float* out = (float*)d_out;

    char* ws = (char*)d_ws;
    size_t off = 0;
    auto alloc = [&](size_t bytes) {
        off = (off + 255) & ~(size_t)255;
        size_t o = off; off += bytes; return o;
    };
    float2* field  = (float2*)(ws + alloc((size_t)NN * NN * 8));
    float*  kgamma = (float*) (ws + alloc((size_t)NN * NN * 4));
    float2* tw     = (float2*)(ws + alloc((size_t)NN * 8));
    float2* R1     = (float2*)(ws + alloc((size_t)NN * NN * 8));
    float2* Ef     = (float2*)(ws + alloc((size_t)NN * NN * 8));
    float2* part   = (float2*)(ws + alloc((size_t)NE * PW * NN * 8));
    float*  psf    = (float*) (ws + alloc((size_t)NE * PW * PW * 4));
    float*  scales = (float*) (ws + alloc((size_t)NE * 4));
    float*  kern   = (float*) (ws + alloc((size_t)64 * 4));
    float*  canvas = (float*) (ws + alloc((size_t)BATCH * CAN * CAN * 4));
    (void)ws_size; (void)n_in; (void)in_sizes; (void)out_size;

    k_init<<<dim3((NN * NN + 255) / 256), 256, 0, stream>>>(phase, field, kgamma, tw);
    k_zero<<<(BATCH * CAN * CAN + 255) / 256, 256, 0, stream>>>(canvas, BATCH * CAN * CAN);
    // fft2: rows then cols (forward, sign=-1)
    k_dft500<<<NN, 256, 0, stream>>>(field, R1, tw, NN, 1, NN, 1, -1.0f);
    k_dft500<<<NN, 256, 0, stream>>>(R1, Ef, tw, 1, NN, 1, NN, -1.0f);
    // partial inverse transforms for the 31x31 crop, all 64 z-planes
    k_prop_rows<<<dim3(NN, 2), 256, 0, stream>>>(Ef, kgamma, zs, part);
    k_prop_cols<<<dim3(PW, NE), 256, 0, stream>>>(part, psf);
    k_norm<<<NE, 256, 0, stream>>>(psf, scales);
    k_kern<<<1, 64, 0, stream>>>(std_u, kern);
    k_scatter<<<dim3(NE, BATCH), 256, 0, stream>>>(psf, scales, xyz, canvas);
    k_final<<<(BATCH * OHW * OHW + 255) / 256, 256, 0, stream>>>(canvas, kern, epsd, epsp, epsr, out);
}

// Round 6
// 239.750 us; speedup vs baseline: 1.3119x; 1.0835x over previous
//
#include <hip/hip_runtime.h>
#include <math.h>

#define NN 500
#define NE 64
#define BATCH 8
#define RR 15
#define PW 31            // 2R+1
#define CAN 200
#define OHW 198
#define TWO_PI_F 6.28318530717958647692f

// ---------------------------------------------------------------------------
// K0: build pupil field, K*GAMMA table, and 500-pt twiddle table
// ---------------------------------------------------------------------------
__global__ void k_init(const float* __restrict__ phase,
                       float2* __restrict__ field,
                       float* __restrict__ kgamma,
                       float2* __restrict__ tw) {
    int idx = blockIdx.x * blockDim.x + threadIdx.x;
    if (idx < NN) {
        double th = 2.0 * M_PI * (double)idx / (double)NN;
        tw[idx] = make_float2((float)cos(th), (float)sin(th));
    }
    if (idx >= NN * NN) return;
    int i = idx / NN, j = idx % NN;

    double x = (double)(j - 250) * 1e-6;
    double y = (double)(i - 250) * 1e-6;
    double r2 = x * x + y * y;
    double inc_d = exp(-r2 / (2.0 * 1.5e-4 * 1.5e-4));
    double c1 = fmod(M_PI / (5.32e-7 * 0.1) * r2, 2.0 * M_PI);
    float inc = (float)inc_d;
    float b1r = (float)cos(c1);
    float b1i = (float)(-sin(c1));
    float ph = phase[idx];
    float sp, cp;
    sincosf(ph, &sp, &cp);
    float ar = inc * cp, ai = inc * sp;
    field[idx] = make_float2(ar * b1r - ai * b1i, ar * b1i + ai * b1r);

    double fy = (double)((i < 250) ? i : i - 500) * 2000.0;
    double fx = (double)((j < 250) ? j : j - 500) * 2000.0;
    double a = 5.32e-7 * fx;
    double b = 5.32e-7 * fy;
    double g = 1.0 - a * a - b * b;
    g = (g > 0.0) ? sqrt(g) : 0.0;
    float Kf = (float)(2.0 * M_PI * 1.0 / 5.32e-7);
    kgamma[idx] = Kf * (float)g;
}

// ---------------------------------------------------------------------------
// Full 500-pt DFT along one axis via Cooley-Tukey 20x25:
//   n = 25a + b (a<20, b<25): X[k] = sum_b W^{kb} * S[b][k mod 20],
//   S[b][d] = sum_a x[25a+b] * w20^{ad},  w20 = W^25.
// Stage 1 pairs (d, d+10) via (-1)^a; stage 2 pairs (k, k+250) via (-1)^b.
// 22.5K cmacs/line vs 250K for the direct DFT.
// ---------------------------------------------------------------------------
__global__ void k_dft500(const float2* __restrict__ src, float2* __restrict__ dst,
                         const float2* __restrict__ tw,
                         int src_line, int src_elem, int dst_line, int dst_elem,
                         float sgn) {
    __shared__ __align__(16) float2 xs[NN];
    __shared__ float2 tts[NN];
    __shared__ float2 S[25 * 21];          // S[b*21 + d], padded stride 21
    int line = blockIdx.x;
    const float2* s = src + (size_t)line * src_line;
    int t = threadIdx.x;
    for (int n = t; n < NN; n += 256) {
        xs[n] = s[(size_t)n * src_elem];
        float2 tt = tw[n];
        tts[n] = make_float2(tt.x, sgn * tt.y);
    }
    __syncthreads();
    // stage 1: t < 250 -> (b = t%25, d = t/25 in [0,10)), also d+10 via parity
    if (t < 250) {
        int d = t / 25;
        int b = t % 25;
        float2 st = tts[(25 * d) % NN];    // w20^d (exact)
        float wr = 1.f, wi = 0.f;          // w20^{a d} at a=0
        float Er = 0.f, Ei = 0.f, Or_ = 0.f, Oi = 0.f;
#pragma unroll
        for (int a = 0; a < 20; a += 2) {
            float2 x0 = xs[25 * a + b];
            Er += x0.x * wr - x0.y * wi;
            Ei += x0.x * wi + x0.y * wr;
            float nr = wr * st.x - wi * st.y;   // advance to a+1
            float ni = wr * st.y + wi * st.x;
            float2 x1 = xs[25 * (a + 1) + b];
            Or_ += x1.x * nr - x1.y * ni;
            Oi  += x1.x * ni + x1.y * nr;
            wr = nr * st.x - ni * st.y;         // advance to a+2
            wi = nr * st.y + ni * st.x;
        }
        S[b * 21 + d]      = make_float2(Er + Or_, Ei + Oi);
        S[b * 21 + d + 10] = make_float2(Er - Or_, Ei - Oi);
    }
    __syncthreads();
    // stage 2: t < 250 -> outputs k = t and k+250
    if (t < 250) {
        int k = t;
        int d1 = k % 20;
        int d2 = (d1 + 10) % 20;
        float2 s1 = tts[k];                // W^k (exact)
        float wr = 1.f, wi = 0.f;          // W^{k b} at b=0
        float a1r = 0.f, a1i = 0.f, a2r = 0.f, a2i = 0.f;
#pragma unroll
        for (int b = 0; b < 25; ++b) {
            float2 u1 = S[b * 21 + d1];
            float2 u2 = S[b * 21 + d2];
            a1r += u1.x * wr - u1.y * wi;
            a1i += u1.x * wi + u1.y * wr;
            float sgnb = (b & 1) ? -1.f : 1.f;   // W^{250 b} = (-1)^b
            float w2r = sgnb * wr, w2i = sgnb * wi;
            a2r += u2.x * w2r - u2.y * w2i;
            a2i += u2.x * w2i + u2.y * w2r;
            float nr = wr * s1.x - wi * s1.y;
            wi = wr * s1.y + wi * s1.x;
            wr = nr;
        }
        float2* dp = dst + (size_t)line * dst_line;
        dp[(size_t)k * dst_elem] = make_float2(a1r, a1i);
        dp[(size_t)(k + 250) * dst_elem] = make_float2(a2r, a2i);
    }
}

// ---------------------------------------------------------------------------
// B1 v6: block = (u, zq), zq in [0,8) -> one pass of 8 resident z-planes.
// (4000 blocks for steady 5 blocks/CU occupancy and a short tail.)
// Wave w handles z rows {2w, 2w+1}. Lane = (co in [0,8), vs in [0,8)):
// Tc=4 c-values per thread, v-dim split 8 ways intra-wave (3 shfl levels).
// Parity fold: sum_v Y[v] w^vc = sum_{v<250} (Y[v] +- Y[v+250]) w^vc.
//   part[z][c][u] = sum_v Ef[u,v]*e^{i*kg[u,v]*z} * e^{+2pi*i*v*c/500}
// ---------------------------------------------------------------------------
__global__ void __launch_bounds__(256, 5)
k_prop_rows(const float2* __restrict__ Ef,
            const float* __restrict__ kgamma,
            const float* __restrict__ zs,
            float2* __restrict__ part) {
    __shared__ __align__(16) float2 Ys[8][NN];   // 32000 B (only LDS)
    int u = blockIdx.x;
    int zbase = blockIdx.y * 8;
    int t = threadIdx.x;
    int w = t >> 6;             // wave id 0..3 -> z rows 2w, 2w+1
    int lane = t & 63;
    int co = lane >> 3;         // 0..7 : c-quad index (bits 3..5)
    int vs = lane & 7;          // 0..7 : v-segment (bits 0..2)
    int c0 = 235 + 4 * co;      // c = c0..c0+3 (co=7,cl=3 -> 266 dummy)

    const float2* erow = Ef + (size_t)u * NN;
    const float* grow = kgamma + (size_t)u * NN;

    // rotators per cl: w0 = e^{+2pi i (2 vs c)/500} (column v=2vs),
    // s1 = e^{+2pi i c/500} (v -> v+1), st = e^{+2pi i 16c/500} (pair-col += 8)
    float w0r[4], w0i[4], s1r[4], s1i[4], str[4], sti[4];
#pragma unroll
    for (int cl = 0; cl < 4; ++cl) {
        int c = c0 + cl;
        float th0 = (TWO_PI_F / NN) * (float)((2 * vs * c) % NN);
        sincosf(th0, &w0i[cl], &w0r[cl]);
        float th1 = (TWO_PI_F / NN) * (float)(c % NN);
        sincosf(th1, &s1i[cl], &s1r[cl]);
        float ths = (TWO_PI_F / NN) * (float)((16 * c) % NN);
        sincosf(ths, &sti[cl], &str[cl]);
    }

    float zv[8];
#pragma unroll
    for (int zi = 0; zi < 8; ++zi) zv[zi] = zs[zbase + zi];
    // modulate: Ys[zi][v] = Ef[u,v] * e^{i*kg[u,v]*z}
    for (int v = t; v < NN; v += 256) {
        float2 e = erow[v];
        float kg = grow[v];
#pragma unroll
        for (int zi = 0; zi < 8; ++zi) {
            float s, cc;
            sincosf(kg * zv[zi], &s, &cc);
            Ys[zi][v] = make_float2(e.x * cc - e.y * s, e.x * s + e.y * cc);
        }
    }
    __syncthreads();

    // partial DFT with parity fold: acc[cl][j], j = z row 2w+j
    float wr[4], wi[4];
#pragma unroll
    for (int cl = 0; cl < 4; ++cl) { wr[cl] = w0r[cl]; wi[cl] = w0i[cl]; }
    float accr[4][2], acci[4][2];
#pragma unroll
    for (int cl = 0; cl < 4; ++cl)
#pragma unroll
        for (int j = 0; j < 2; ++j) { accr[cl][j] = 0.f; acci[cl][j] = 0.f; }

    for (int pc = vs; pc < 125; pc += 8) {   // pair-columns: v=2pc, 2pc+1
        int v = 2 * pc;
        float4 x0a = *(const float4*)&Ys[2 * w + 0][v];        // z0: v, v+1
        float4 x0b = *(const float4*)&Ys[2 * w + 0][v + 250];  // z0: v+250, v+251
        float4 x1a = *(const float4*)&Ys[2 * w + 1][v];        // z1
        float4 x1b = *(const float4*)&Ys[2 * w + 1][v + 250];
        // parity sums: e = a+b (even c), o = a-b (odd c); per z, per column
        float e0vr = x0a.x + x0b.x, e0vi = x0a.y + x0b.y;
        float o0vr = x0a.x - x0b.x, o0vi = x0a.y - x0b.y;
        float e0wr_ = x0a.z + x0b.z, e0wi_ = x0a.w + x0b.w;
        float o0wr_ = x0a.z - x0b.z, o0wi_ = x0a.w - x0b.w;
        float e1vr = x1a.x + x1b.x, e1vi = x1a.y + x1b.y;
        float o1vr = x1a.x - x1b.x, o1vi = x1a.y - x1b.y;
        float e1wr_ = x1a.z + x1b.z, e1wi_ = x1a.w + x1b.w;
        float o1wr_ = x1a.z - x1b.z, o1wi_ = x1a.w - x1b.w;
#pragma unroll
        for (int cl = 0; cl < 4; ++cl) {
            float ar = wr[cl], ai = wi[cl];              // twiddle at v
            float br = ar * s1r[cl] - ai * s1i[cl];      // twiddle at v+1
            float bi = ar * s1i[cl] + ai * s1r[cl];
            // c = c0+cl, c0 odd: cl even -> c odd (use o), cl odd -> c even (use e)
            if ((cl & 1) == 0) {
                accr[cl][0] += o0vr * ar - o0vi * ai + o0wr_ * br - o0wi_ * bi;
                acci[cl][0] += o0vr * ai + o0vi * ar + o0wr_ * bi + o0wi_ * br;
                accr[cl][1] += o1vr * ar - o1vi * ai + o1wr_ * br - o1wi_ * bi;
                acci[cl][1] += o1vr * ai + o1vi * ar + o1wr_ * bi + o1wi_ * br;
            } else {
                accr[cl][0] += e0vr * ar - e0vi * ai + e0wr_ * br - e0wi_ * bi;
                acci[cl][0] += e0vr * ai + e0vi * ar + e0wr_ * bi + e0wi_ * br;
                accr[cl][1] += e1vr * ar - e1vi * ai + e1wr_ * br - e1wi_ * bi;
                acci[cl][1] += e1vr * ai + e1vi * ar + e1wr_ * bi + e1wi_ * br;
            }
            float nwr = ar * str[cl] - ai * sti[cl];     // advance pair-col
            wi[cl] = ar * sti[cl] + ai * str[cl];
            wr[cl] = nwr;
        }
    }

    // reduce over vs (lane bits 0..2)
#pragma unroll
    for (int cl = 0; cl < 4; ++cl)
#pragma unroll
        for (int j = 0; j < 2; ++j) {
#pragma unroll
            for (int m = 1; m < 8; m <<= 1) {
                accr[cl][j] += __shfl_xor(accr[cl][j], m);
                acci[cl][j] += __shfl_xor(acci[cl][j], m);
            }
        }
    if (vs == 0) {
#pragma unroll
        for (int cl = 0; cl < 4; ++cl) {
            int c = c0 + cl;
            if (c <= 265) {
#pragma unroll
                for (int j = 0; j < 2; ++j) {
                    int z = zbase + 2 * w + j;
                    part[((size_t)z * PW + (c - 235)) * NN + u] =
                        make_float2(accr[cl][j], acci[cl][j]);
                }
            }
        }
    }
}

// ---------------------------------------------------------------------------
// B2: per (z,c): Eprop[r,c] = (1/500^2) * sum_u part[z][c][u]*e^{+2pi*i*u*r/500}
// ---------------------------------------------------------------------------
__global__ void k_prop_cols(const float2* __restrict__ part,
                            float* __restrict__ psf) {
    __shared__ float2 X[NN];
    int ci = blockIdx.x;   // 31
    int z = blockIdx.y;    // 64
    int t = threadIdx.x;
    const float2* col = part + ((size_t)z * PW + ci) * NN;
    for (int u = t; u < NN; u += 256) X[u] = col[u];
    __syncthreads();
    if (t < PW * 8) {
        int ri = t >> 3, seg = t & 7;
        int r = 235 + ri;
        float wr, wi, sr, si;
        {
            float th0 = (TWO_PI_F / NN) * (float)((seg * r) % NN);
            sincosf(th0, &wi, &wr);
            float ths = (TWO_PI_F / NN) * (float)((8 * r) % NN);
            sincosf(ths, &si, &sr);
        }
        float ar = 0.f, ai = 0.f;
        for (int u = seg; u < NN; u += 8) {
            float2 xv = X[u];
            ar += xv.x * wr - xv.y * wi;
            ai += xv.x * wi + xv.y * wr;
            float nwr = wr * sr - wi * si;
            wi = wr * si + wi * sr;
            wr = nwr;
        }
#pragma unroll
        for (int m = 1; m < 8; m <<= 1) {
            ar += __shfl_xor(ar, m);
            ai += __shfl_xor(ai, m);
        }
        if (seg == 0 && ri < PW) {
            const float inv = 1.0f / 250000.0f;
            float re = ar * inv, im = ai * inv;
            psf[(size_t)z * (PW * PW) + ri * PW + ci] = re * re + im * im;
        }
    }
}

// ---------------------------------------------------------------------------
__global__ void k_norm(const float* __restrict__ psf, float* __restrict__ scales) {
    __shared__ float red[256];
    int z = blockIdx.x;
    float s = 0.f;
    for (int p = threadIdx.x; p < PW * PW; p += 256) s += psf[z * PW * PW + p];
    red[threadIdx.x] = s;
    __syncthreads();
    for (int o = 128; o > 0; o >>= 1) {
        if (threadIdx.x < o) red[threadIdx.x] += red[threadIdx.x + o];
        __syncthreads();
    }
    if (threadIdx.x == 0) scales[z] = 1.0e6f / (red[0] + 1e-12f);
}

__global__ void k_kern(const float* __restrict__ std_u, float* __restrict__ kern) {
    int t = threadIdx.x;
    if (t < 49) {
        float stdv = 0.8f + 0.4f * std_u[0];
        float s2 = stdv * stdv;
        int a = t / 7 - 3, b = t % 7 - 3;
        float g = (float)exp(-0.5 * (double)(a * a + b * b));
        kern[t] = (1.0f / (2.0f * (float)M_PI * s2)) * powf(g, 1.0f / s2);
    }
}

__global__ void k_zero(float* __restrict__ p, int n) {
    int i = blockIdx.x * blockDim.x + threadIdx.x;
    if (i < n) p[i] = 0.f;
}

__global__ void k_scatter(const float* __restrict__ psf,
                          const float* __restrict__ scales,
                          const int* __restrict__ xyz,
                          float* __restrict__ canvas) {
    int e = blockIdx.x;
    int b = blockIdx.y;
    int r0 = xyz[(b * NE + e) * 2 + 0] - RR;
    int c0 = xyz[(b * NE + e) * 2 + 1] - RR;
    float sc = scales[e];
    float* cb = canvas + (size_t)b * (CAN * CAN);
    for (int p = threadIdx.x; p < PW * PW; p += blockDim.x) {
        int i = p / PW, j = p % PW;
        atomicAdd(cb + (r0 + i) * CAN + (c0 + j), psf[e * PW * PW + p] * sc);
    }
}

__global__ void k_final(const float* __restrict__ canvas,
                        const float* __restrict__ kern,
                        const float* __restrict__ eps_dark,
                        const float* __restrict__ eps_photon,
                        const float* __restrict__ eps_read,
                        float* __restrict__ out) {
    __shared__ float kk[49];
    if (threadIdx.x < 49) kk[threadIdx.x] = kern[threadIdx.x];
    __syncthreads();
    int idx = blockIdx.x * blockDim.x + threadIdx.x;
    if (idx >= BATCH * OHW * OHW) return;
    int b = idx / (OHW * OHW);
    int rem = idx % (OHW * OHW);
    int i = rem / OHW, j = rem % OHW;
    const float* cb = canvas + (size_t)b * (CAN * CAN);
    float acc = 0.f;
#pragma unroll
    for (int a = 0; a < 7; ++a) {
        int r = i + a - 2;
        if (r < 0 || r >= CAN) continue;
#pragma unroll
        for (int q = 0; q < 7; ++q) {
            int c = j + q - 2;
            if (c < 0 || c >= CAN) continue;
            acc += cb[r * CAN + c] * kk[a * 7 + q];
        }
    }
    float sig = acc * 0.9f;
    float dark = 0.005f + eps_dark[idx] * sqrtf(0.005f);
    float total = fmaxf(sig + dark, 0.0f);
    float noisy = total + eps_photon[idx] * sqrtf(fmaxf(total, 1e-12f));
    float elec = noisy + eps_read[idx] * 1.6f;
    float adu = fminf(fmaxf(elec * 2.0f, 0.0f), 65535.0f);
    float v = (adu <= 10.0f) ? 1.0f : fminf(adu, 4.0e9f);
    out[idx] = v / 4.0e9f;
}

// ---------------------------------------------------------------------------
extern "C" void kernel_launch(void* const* d_in, const int* in_sizes, int n_in,
                              void* d_out, int out_size, void* d_ws, size_t ws_size,
                              hipStream_t stream) {
    const float* phase    = (const float*)d_in[0];
    const float* zs       = (const float*)d_in[1];
    const int*   xyz      = (const int*)d_in[2];
    const float* std_u    = (const float*)d_in[3];
    const float* epsd     = (const float*)d_in[4];
    const float* epsp     = (const float*)d_in[5];
    const float* epsr     = (const float*)d_in[6];
    float* out = (float*)d_out;

    char* ws = (char*)d_ws;
    size_t off = 0;
    auto alloc = [&](size_t bytes) {
        off = (off + 255) & ~(size_t)255;
        size_t o = off; off += bytes; return o;
    };
    float2* field  = (float2*)(ws + alloc((size_t)NN * NN * 8));
    float*  kgamma = (float*) (ws + alloc((size_t)NN * NN * 4));
    float2* tw     = (float2*)(ws + alloc((size_t)NN * 8));
    float2* R1     = (float2*)(ws + alloc((size_t)NN * NN * 8));
    float2* Ef     = (float2*)(ws + alloc((size_t)NN * NN * 8));
    float2* part   = (float2*)(ws + alloc((size_t)NE * PW * NN * 8));
    float*  psf    = (float*) (ws + alloc((size_t)NE * PW * PW * 4));
    float*  scales = (float*) (ws + alloc((size_t)NE * 4));
    float*  kern   = (float*) (ws + alloc((size_t)64 * 4));
    float*  canvas = (float*) (ws + alloc((size_t)BATCH * CAN * CAN * 4));
    (void)ws_size; (void)n_in; (void)in_sizes; (void)out_size;

    k_init<<<dim3((NN * NN + 255) / 256), 256, 0, stream>>>(phase, field, kgamma, tw);
    k_zero<<<(BATCH * CAN * CAN + 255) / 256, 256, 0, stream>>>(canvas, BATCH * CAN * CAN);
    // fft2: rows then cols (forward, sign=-1), CT 20x25 per line
    k_dft500<<<NN, 256, 0, stream>>>(field, R1, tw, NN, 1, NN, 1, -1.0f);
    k_dft500<<<NN, 256, 0, stream>>>(R1, Ef, tw, 1, NN, 1, NN, -1.0f);
    // partial inverse transforms for the 31x31 crop, all 64 z-planes
    k_prop_rows<<<dim3(NN, 8), 256, 0, stream>>>(Ef, kgamma, zs, part);
    k_prop_cols<<<dim3(PW, NE), 256, 0, stream>>>(part, psf);
    k_norm<<<NE, 256, 0, stream>>>(psf, scales);
    k_kern<<<1, 64, 0, stream>>>(std_u, kern);
    k_scatter<<<dim3(NE, BATCH), 256, 0, stream>>>(psf, scales, xyz, canvas);
    k_final<<<(BATCH * OHW * OHW + 255) / 256, 256, 0, stream>>>(canvas, kern, epsd, epsp, epsr, out);
}

// Round 7
// 208.297 us; speedup vs baseline: 1.5100x; 1.1510x over previous
//
#include <hip/hip_runtime.h>
#include <math.h>

#define NN 500
#define NE 64
#define BATCH 8
#define RR 15
#define PW 31            // 2R+1
#define CAN 200
#define OHW 198
#define TWO_PI_F 6.28318530717958647692f

// Fast accurate sincos for |theta| up to ~1200 rad: Cody-Waite 2-term
// reduction (n <= 188, fma single-rounding => err ~2.5e-7 rad) + hardware
// v_sin/v_cos via __sinf/__cosf on the reduced |r| <= pi argument.
__device__ __forceinline__ void fast_sincos_red(float theta, float* s, float* c) {
    const float INV2PI = 0.15915494309189535f;
    const float PI2_HI = 6.28318548202514648f;   // f32(2*pi)
    const float PI2_LO = -1.7484556e-7f;         // 2*pi - PI2_HI
    float n = rintf(theta * INV2PI);
    float r = fmaf(n, -PI2_HI, theta);
    r = fmaf(n, -PI2_LO, r);
    *s = __sinf(r);
    *c = __cosf(r);
}

// ---------------------------------------------------------------------------
// K0: build pupil field, K*GAMMA table, and 500-pt twiddle table
// ---------------------------------------------------------------------------
__global__ void k_init(const float* __restrict__ phase,
                       float2* __restrict__ field,
                       float* __restrict__ kgamma,
                       float2* __restrict__ tw) {
    int idx = blockIdx.x * blockDim.x + threadIdx.x;
    if (idx < NN) {
        double th = 2.0 * M_PI * (double)idx / (double)NN;
        tw[idx] = make_float2((float)cos(th), (float)sin(th));
    }
    if (idx >= NN * NN) return;
    int i = idx / NN, j = idx % NN;

    double x = (double)(j - 250) * 1e-6;
    double y = (double)(i - 250) * 1e-6;
    double r2 = x * x + y * y;
    double inc_d = exp(-r2 / (2.0 * 1.5e-4 * 1.5e-4));
    double c1 = fmod(M_PI / (5.32e-7 * 0.1) * r2, 2.0 * M_PI);
    float inc = (float)inc_d;
    float b1r = (float)cos(c1);
    float b1i = (float)(-sin(c1));
    float ph = phase[idx];
    float sp, cp;
    sincosf(ph, &sp, &cp);
    float ar = inc * cp, ai = inc * sp;
    field[idx] = make_float2(ar * b1r - ai * b1i, ar * b1i + ai * b1r);

    double fy = (double)((i < 250) ? i : i - 500) * 2000.0;
    double fx = (double)((j < 250) ? j : j - 500) * 2000.0;
    double a = 5.32e-7 * fx;
    double b = 5.32e-7 * fy;
    double g = 1.0 - a * a - b * b;
    g = (g > 0.0) ? sqrt(g) : 0.0;
    float Kf = (float)(2.0 * M_PI * 1.0 / 5.32e-7);
    kgamma[idx] = Kf * (float)g;
}

// ---------------------------------------------------------------------------
// Full 500-pt DFT along one axis via Cooley-Tukey 20x25:
//   n = 25a + b (a<20, b<25): X[k] = sum_b W^{kb} * S[b][k mod 20],
//   S[b][d] = sum_a x[25a+b] * w20^{ad},  w20 = W^25.
// Stage 1 pairs (d, d+10) via (-1)^a; stage 2 pairs (k, k+250) via (-1)^b.
// ---------------------------------------------------------------------------
__global__ void k_dft500(const float2* __restrict__ src, float2* __restrict__ dst,
                         const float2* __restrict__ tw,
                         int src_line, int src_elem, int dst_line, int dst_elem,
                         float sgn) {
    __shared__ __align__(16) float2 xs[NN];
    __shared__ float2 tts[NN];
    __shared__ float2 S[25 * 21];          // S[b*21 + d], padded stride 21
    int line = blockIdx.x;
    const float2* s = src + (size_t)line * src_line;
    int t = threadIdx.x;
    for (int n = t; n < NN; n += 256) {
        xs[n] = s[(size_t)n * src_elem];
        float2 tt = tw[n];
        tts[n] = make_float2(tt.x, sgn * tt.y);
    }
    __syncthreads();
    // stage 1: t < 250 -> (b = t%25, d = t/25 in [0,10)), also d+10 via parity
    if (t < 250) {
        int d = t / 25;
        int b = t % 25;
        float2 st = tts[(25 * d) % NN];    // w20^d (exact)
        float wr = 1.f, wi = 0.f;          // w20^{a d} at a=0
        float Er = 0.f, Ei = 0.f, Or_ = 0.f, Oi = 0.f;
#pragma unroll
        for (int a = 0; a < 20; a += 2) {
            float2 x0 = xs[25 * a + b];
            Er += x0.x * wr - x0.y * wi;
            Ei += x0.x * wi + x0.y * wr;
            float nr = wr * st.x - wi * st.y;   // advance to a+1
            float ni = wr * st.y + wi * st.x;
            float2 x1 = xs[25 * (a + 1) + b];
            Or_ += x1.x * nr - x1.y * ni;
            Oi  += x1.x * ni + x1.y * nr;
            wr = nr * st.x - ni * st.y;         // advance to a+2
            wi = nr * st.y + ni * st.x;
        }
        S[b * 21 + d]      = make_float2(Er + Or_, Ei + Oi);
        S[b * 21 + d + 10] = make_float2(Er - Or_, Ei - Oi);
    }
    __syncthreads();
    // stage 2: t < 250 -> outputs k = t and k+250
    if (t < 250) {
        int k = t;
        int d1 = k % 20;
        int d2 = (d1 + 10) % 20;
        float2 s1 = tts[k];                // W^k (exact)
        float wr = 1.f, wi = 0.f;          // W^{k b} at b=0
        float a1r = 0.f, a1i = 0.f, a2r = 0.f, a2i = 0.f;
#pragma unroll
        for (int b = 0; b < 25; ++b) {
            float2 u1 = S[b * 21 + d1];
            float2 u2 = S[b * 21 + d2];
            a1r += u1.x * wr - u1.y * wi;
            a1i += u1.x * wi + u1.y * wr;
            float sgnb = (b & 1) ? -1.f : 1.f;   // W^{250 b} = (-1)^b
            float w2r = sgnb * wr, w2i = sgnb * wi;
            a2r += u2.x * w2r - u2.y * w2i;
            a2i += u2.x * w2i + u2.y * w2r;
            float nr = wr * s1.x - wi * s1.y;
            wi = wr * s1.y + wi * s1.x;
            wr = nr;
        }
        float2* dp = dst + (size_t)line * dst_line;
        dp[(size_t)k * dst_elem] = make_float2(a1r, a1i);
        dp[(size_t)(k + 250) * dst_elem] = make_float2(a2r, a2i);
    }
}

// ---------------------------------------------------------------------------
// B1 v7: v5 structure (grid (u, zhalf), 1000 blocks all-resident, 4 passes of
// 8 z) + fast modulate sincos. Wave w handles z rows {2w, 2w+1}. Lane =
// (co in [0,8), vs in [0,8)): Tc=4 c per thread, v split 8 ways intra-wave.
// Parity fold: sum_v Y[v] w^vc = sum_{v<250} (Y[v] +- Y[v+250]) w^vc.
//   part[z][c][u] = sum_v Ef[u,v]*e^{i*kg[u,v]*z} * e^{+2pi*i*v*c/500}
// ---------------------------------------------------------------------------
__global__ void __launch_bounds__(256, 5)
k_prop_rows(const float2* __restrict__ Ef,
            const float* __restrict__ kgamma,
            const float* __restrict__ zs,
            float2* __restrict__ part) {
    __shared__ __align__(16) float2 Ys[8][NN];   // 32000 B (only LDS)
    int u = blockIdx.x;
    int zhalf = blockIdx.y;
    int t = threadIdx.x;
    int w = t >> 6;             // wave id 0..3 -> z rows 2w, 2w+1
    int lane = t & 63;
    int co = lane >> 3;         // 0..7 : c-quad index (bits 3..5)
    int vs = lane & 7;          // 0..7 : v-segment (bits 0..2)
    int c0 = 235 + 4 * co;      // c = c0..c0+3 (co=7,cl=3 -> 266 dummy)

    const float2* erow = Ef + (size_t)u * NN;
    const float* grow = kgamma + (size_t)u * NN;

    // rotators per cl (exact sincosf, amortized over 4 passes):
    // w0 = e^{+2pi i (2 vs c)/500}, s1 = e^{+2pi i c/500}, st = e^{+2pi i 16c/500}
    float w0r[4], w0i[4], s1r[4], s1i[4], str[4], sti[4];
#pragma unroll
    for (int cl = 0; cl < 4; ++cl) {
        int c = c0 + cl;
        float th0 = (TWO_PI_F / NN) * (float)((2 * vs * c) % NN);
        sincosf(th0, &w0i[cl], &w0r[cl]);
        float th1 = (TWO_PI_F / NN) * (float)(c % NN);
        sincosf(th1, &s1i[cl], &s1r[cl]);
        float ths = (TWO_PI_F / NN) * (float)((16 * c) % NN);
        sincosf(ths, &sti[cl], &str[cl]);
    }

    for (int g = 0; g < 4; ++g) {
        int zbase = zhalf * 32 + g * 8;
        float zv[8];
#pragma unroll
        for (int zi = 0; zi < 8; ++zi) zv[zi] = zs[zbase + zi];
        // modulate: Ys[zi][v] = Ef[u,v] * e^{i*kg[u,v]*z}  (fast sincos)
        for (int v = t; v < NN; v += 256) {
            float2 e = erow[v];
            float kg = grow[v];
#pragma unroll
            for (int zi = 0; zi < 8; ++zi) {
                float s, cc;
                fast_sincos_red(kg * zv[zi], &s, &cc);
                Ys[zi][v] = make_float2(e.x * cc - e.y * s, e.x * s + e.y * cc);
            }
        }
        __syncthreads();

        // partial DFT with parity fold: acc[cl][j], j = z row 2w+j
        float wr[4], wi[4];
#pragma unroll
        for (int cl = 0; cl < 4; ++cl) { wr[cl] = w0r[cl]; wi[cl] = w0i[cl]; }
        float accr[4][2], acci[4][2];
#pragma unroll
        for (int cl = 0; cl < 4; ++cl)
#pragma unroll
            for (int j = 0; j < 2; ++j) { accr[cl][j] = 0.f; acci[cl][j] = 0.f; }

        for (int pc = vs; pc < 125; pc += 8) {   // pair-columns: v=2pc, 2pc+1
            int v = 2 * pc;
            float4 x0a = *(const float4*)&Ys[2 * w + 0][v];
            float4 x0b = *(const float4*)&Ys[2 * w + 0][v + 250];
            float4 x1a = *(const float4*)&Ys[2 * w + 1][v];
            float4 x1b = *(const float4*)&Ys[2 * w + 1][v + 250];
            float e0vr = x0a.x + x0b.x, e0vi = x0a.y + x0b.y;
            float o0vr = x0a.x - x0b.x, o0vi = x0a.y - x0b.y;
            float e0wr_ = x0a.z + x0b.z, e0wi_ = x0a.w + x0b.w;
            float o0wr_ = x0a.z - x0b.z, o0wi_ = x0a.w - x0b.w;
            float e1vr = x1a.x + x1b.x, e1vi = x1a.y + x1b.y;
            float o1vr = x1a.x - x1b.x, o1vi = x1a.y - x1b.y;
            float e1wr_ = x1a.z + x1b.z, e1wi_ = x1a.w + x1b.w;
            float o1wr_ = x1a.z - x1b.z, o1wi_ = x1a.w - x1b.w;
#pragma unroll
            for (int cl = 0; cl < 4; ++cl) {
                float ar = wr[cl], ai = wi[cl];              // twiddle at v
                float br = ar * s1r[cl] - ai * s1i[cl];      // twiddle at v+1
                float bi = ar * s1i[cl] + ai * s1r[cl];
                if ((cl & 1) == 0) {   // c odd -> odd-parity sums
                    accr[cl][0] += o0vr * ar - o0vi * ai + o0wr_ * br - o0wi_ * bi;
                    acci[cl][0] += o0vr * ai + o0vi * ar + o0wr_ * bi + o0wi_ * br;
                    accr[cl][1] += o1vr * ar - o1vi * ai + o1wr_ * br - o1wi_ * bi;
                    acci[cl][1] += o1vr * ai + o1vi * ar + o1wr_ * bi + o1wi_ * br;
                } else {               // c even -> even-parity sums
                    accr[cl][0] += e0vr * ar - e0vi * ai + e0wr_ * br - e0wi_ * bi;
                    acci[cl][0] += e0vr * ai + e0vi * ar + e0wr_ * bi + e0wi_ * br;
                    accr[cl][1] += e1vr * ar - e1vi * ai + e1wr_ * br - e1wi_ * bi;
                    acci[cl][1] += e1vr * ai + e1vi * ar + e1wr_ * bi + e1wi_ * br;
                }
                float nwr = ar * str[cl] - ai * sti[cl];     // advance pair-col
                wi[cl] = ar * sti[cl] + ai * str[cl];
                wr[cl] = nwr;
            }
        }

        // reduce over vs (lane bits 0..2)
#pragma unroll
        for (int cl = 0; cl < 4; ++cl)
#pragma unroll
            for (int j = 0; j < 2; ++j) {
#pragma unroll
                for (int m = 1; m < 8; m <<= 1) {
                    accr[cl][j] += __shfl_xor(accr[cl][j], m);
                    acci[cl][j] += __shfl_xor(acci[cl][j], m);
                }
            }
        if (vs == 0) {
#pragma unroll
            for (int cl = 0; cl < 4; ++cl) {
                int c = c0 + cl;
                if (c <= 265) {
#pragma unroll
                    for (int j = 0; j < 2; ++j) {
                        int z = zbase + 2 * w + j;
                        part[((size_t)z * PW + (c - 235)) * NN + u] =
                            make_float2(accr[cl][j], acci[cl][j]);
                    }
                }
            }
        }
        __syncthreads();
    }
}

// ---------------------------------------------------------------------------
// B2: per (z,c): Eprop[r,c] = (1/500^2) * sum_u part[z][c][u]*e^{+2pi*i*u*r/500}
// ---------------------------------------------------------------------------
__global__ void k_prop_cols(const float2* __restrict__ part,
                            float* __restrict__ psf) {
    __shared__ float2 X[NN];
    int ci = blockIdx.x;   // 31
    int z = blockIdx.y;    // 64
    int t = threadIdx.x;
    const float2* col = part + ((size_t)z * PW + ci) * NN;
    for (int u = t; u < NN; u += 256) X[u] = col[u];
    __syncthreads();
    if (t < PW * 8) {
        int ri = t >> 3, seg = t & 7;
        int r = 235 + ri;
        float wr, wi, sr, si;
        {
            float th0 = (TWO_PI_F / NN) * (float)((seg * r) % NN);
            sincosf(th0, &wi, &wr);
            float ths = (TWO_PI_F / NN) * (float)((8 * r) % NN);
            sincosf(ths, &si, &sr);
        }
        float ar = 0.f, ai = 0.f;
        for (int u = seg; u < NN; u += 8) {
            float2 xv = X[u];
            ar += xv.x * wr - xv.y * wi;
            ai += xv.x * wi + xv.y * wr;
            float nwr = wr * sr - wi * si;
            wi = wr * si + wi * sr;
            wr = nwr;
        }
#pragma unroll
        for (int m = 1; m < 8; m <<= 1) {
            ar += __shfl_xor(ar, m);
            ai += __shfl_xor(ai, m);
        }
        if (seg == 0 && ri < PW) {
            const float inv = 1.0f / 250000.0f;
            float re = ar * inv, im = ai * inv;
            psf[(size_t)z * (PW * PW) + ri * PW + ci] = re * re + im * im;
        }
    }
}

// ---------------------------------------------------------------------------
__global__ void k_norm(const float* __restrict__ psf, float* __restrict__ scales) {
    __shared__ float red[256];
    int z = blockIdx.x;
    float s = 0.f;
    for (int p = threadIdx.x; p < PW * PW; p += 256) s += psf[z * PW * PW + p];
    red[threadIdx.x] = s;
    __syncthreads();
    for (int o = 128; o > 0; o >>= 1) {
        if (threadIdx.x < o) red[threadIdx.x] += red[threadIdx.x + o];
        __syncthreads();
    }
    if (threadIdx.x == 0) scales[z] = 1.0e6f / (red[0] + 1e-12f);
}

__global__ void k_kern(const float* __restrict__ std_u, float* __restrict__ kern) {
    int t = threadIdx.x;
    if (t < 49) {
        float stdv = 0.8f + 0.4f * std_u[0];
        float s2 = stdv * stdv;
        int a = t / 7 - 3, b = t % 7 - 3;
        float g = (float)exp(-0.5 * (double)(a * a + b * b));
        kern[t] = (1.0f / (2.0f * (float)M_PI * s2)) * powf(g, 1.0f / s2);
    }
}

__global__ void k_zero(float* __restrict__ p, int n) {
    int i = blockIdx.x * blockDim.x + threadIdx.x;
    if (i < n) p[i] = 0.f;
}

__global__ void k_scatter(const float* __restrict__ psf,
                          const float* __restrict__ scales,
                          const int* __restrict__ xyz,
                          float* __restrict__ canvas) {
    int e = blockIdx.x;
    int b = blockIdx.y;
    int r0 = xyz[(b * NE + e) * 2 + 0] - RR;
    int c0 = xyz[(b * NE + e) * 2 + 1] - RR;
    float sc = scales[e];
    float* cb = canvas + (size_t)b * (CAN * CAN);
    for (int p = threadIdx.x; p < PW * PW; p += blockDim.x) {
        int i = p / PW, j = p % PW;
        atomicAdd(cb + (r0 + i) * CAN + (c0 + j), psf[e * PW * PW + p] * sc);
    }
}

__global__ void k_final(const float* __restrict__ canvas,
                        const float* __restrict__ kern,
                        const float* __restrict__ eps_dark,
                        const float* __restrict__ eps_photon,
                        const float* __restrict__ eps_read,
                        float* __restrict__ out) {
    __shared__ float kk[49];
    if (threadIdx.x < 49) kk[threadIdx.x] = kern[threadIdx.x];
    __syncthreads();
    int idx = blockIdx.x * blockDim.x + threadIdx.x;
    if (idx >= BATCH * OHW * OHW) return;
    int b = idx / (OHW * OHW);
    int rem = idx % (OHW * OHW);
    int i = rem / OHW, j = rem % OHW;
    const float* cb = canvas + (size_t)b * (CAN * CAN);
    float acc = 0.f;
#pragma unroll
    for (int a = 0; a < 7; ++a) {
        int r = i + a - 2;
        if (r < 0 || r >= CAN) continue;
#pragma unroll
        for (int q = 0; q < 7; ++q) {
            int c = j + q - 2;
            if (c < 0 || c >= CAN) continue;
            acc += cb[r * CAN + c] * kk[a * 7 + q];
        }
    }
    float sig = acc * 0.9f;
    float dark = 0.005f + eps_dark[idx] * sqrtf(0.005f);
    float total = fmaxf(sig + dark, 0.0f);
    float noisy = total + eps_photon[idx] * sqrtf(fmaxf(total, 1e-12f));
    float elec = noisy + eps_read[idx] * 1.6f;
    float adu = fminf(fmaxf(elec * 2.0f, 0.0f), 65535.0f);
    float v = (adu <= 10.0f) ? 1.0f : fminf(adu, 4.0e9f);
    out[idx] = v / 4.0e9f;
}

// ---------------------------------------------------------------------------
extern "C" void kernel_launch(void* const* d_in, const int* in_sizes, int n_in,
                              void* d_out, int out_size, void* d_ws, size_t ws_size,
                              hipStream_t stream) {
    const float* phase    = (const float*)d_in[0];
    const float* zs       = (const float*)d_in[1];
    const int*   xyz      = (const int*)d_in[2];
    const float* std_u    = (const float*)d_in[3];
    const float* epsd     = (const float*)d_in[4];
    const float* epsp     = (const float*)d_in[5];
    const float* epsr     = (const float*)d_in[6];
    float* out = (float*)d_out;

    char* ws = (char*)d_ws;
    size_t off = 0;
    auto alloc = [&](size_t bytes) {
        off = (off + 255) & ~(size_t)255;
        size_t o = off; off += bytes; return o;
    };
    float2* field  = (float2*)(ws + alloc((size_t)NN * NN * 8));
    float*  kgamma = (float*) (ws + alloc((size_t)NN * NN * 4));
    float2* tw     = (float2*)(ws + alloc((size_t)NN * 8));
    float2* R1     = (float2*)(ws + alloc((size_t)NN * NN * 8));
    float2* Ef     = (float2*)(ws + alloc((size_t)NN * NN * 8));
    float2* part   = (float2*)(ws + alloc((size_t)NE * PW * NN * 8));
    float*  psf    = (float*) (ws + alloc((size_t)NE * PW * PW * 4));
    float*  scales = (float*) (ws + alloc((size_t)NE * 4));
    float*  kern   = (float*) (ws + alloc((size_t)64 * 4));
    float*  canvas = (float*) (ws + alloc((size_t)BATCH * CAN * CAN * 4));
    (void)ws_size; (void)n_in; (void)in_sizes; (void)out_size;

    k_init<<<dim3((NN * NN + 255) / 256), 256, 0, stream>>>(phase, field, kgamma, tw);
    k_zero<<<(BATCH * CAN * CAN + 255) / 256, 256, 0, stream>>>(canvas, BATCH * CAN * CAN);
    // fft2: rows then cols (forward, sign=-1), CT 20x25 per line
    k_dft500<<<NN, 256, 0, stream>>>(field, R1, tw, NN, 1, NN, 1, -1.0f);
    k_dft500<<<NN, 256, 0, stream>>>(R1, Ef, tw, 1, NN, 1, NN, -1.0f);
    // partial inverse transforms for the 31x31 crop, all 64 z-planes
    k_prop_rows<<<dim3(NN, 2), 256, 0, stream>>>(Ef, kgamma, zs, part);
    k_prop_cols<<<dim3(PW, NE), 256, 0, stream>>>(part, psf);
    k_norm<<<NE, 256, 0, stream>>>(psf, scales);
    k_kern<<<1, 64, 0, stream>>>(std_u, kern);
    k_scatter<<<dim3(NE, BATCH), 256, 0, stream>>>(psf, scales, xyz, canvas);
    k_final<<<(BATCH * OHW * OHW + 255) / 256, 256, 0, stream>>>(canvas, kern, epsd, epsp, epsr, out);
}

// Round 8
// 197.857 us; speedup vs baseline: 1.5897x; 1.0528x over previous
//
#include <hip/hip_runtime.h>
#include <math.h>

#define NN 500
#define NE 64
#define BATCH 8
#define RR 15
#define PW 31            // 2R+1
#define CAN 200
#define OHW 198
#define TWO_PI_F 6.28318530717958647692f

// Fast accurate sincos for |theta| up to ~1200 rad: Cody-Waite 2-term
// reduction + hardware v_sin/v_cos on the reduced |r| <= pi argument.
__device__ __forceinline__ void fast_sincos_red(float theta, float* s, float* c) {
    const float INV2PI = 0.15915494309189535f;
    const float PI2_HI = 6.28318548202514648f;   // f32(2*pi)
    const float PI2_LO = -1.7484556e-7f;         // 2*pi - PI2_HI
    float n = rintf(theta * INV2PI);
    float r = fmaf(n, -PI2_HI, theta);
    r = fmaf(n, -PI2_LO, r);
    *s = __sinf(r);
    *c = __cosf(r);
}

// ---------------------------------------------------------------------------
// K_prep: pupil field, K*GAMMA table (exactly symmetric), 500-pt twiddle
// table, blur-kernel coefficients, canvas + psf_sums zeroing — one kernel.
// ---------------------------------------------------------------------------
__global__ void k_prep(const float* __restrict__ phase,
                       const float* __restrict__ std_u,
                       float2* __restrict__ field,
                       float* __restrict__ kgamma,
                       float2* __restrict__ tw,
                       float* __restrict__ kern,
                       float* __restrict__ canvas,
                       float* __restrict__ psf_sums) {
    int idx = blockIdx.x * blockDim.x + threadIdx.x;
    if (idx < NN) {
        double th = 2.0 * M_PI * (double)idx / (double)NN;
        tw[idx] = make_float2((float)cos(th), (float)sin(th));
    }
    if (idx < BATCH * CAN * CAN) canvas[idx] = 0.f;
    if (idx >= BATCH * CAN * CAN && idx < BATCH * CAN * CAN + NE)
        psf_sums[idx - BATCH * CAN * CAN] = 0.f;
    if (idx >= BATCH * CAN * CAN + NE && idx < BATCH * CAN * CAN + NE + 49) {
        int t = idx - (BATCH * CAN * CAN + NE);
        float stdv = 0.8f + 0.4f * std_u[0];
        float s2 = stdv * stdv;
        int a = t / 7 - 3, b = t % 7 - 3;
        float g = (float)exp(-0.5 * (double)(a * a + b * b));
        kern[t] = (1.0f / (2.0f * (float)M_PI * s2)) * powf(g, 1.0f / s2);
    }
    if (idx >= NN * NN) return;
    int i = idx / NN, j = idx % NN;

    double x = (double)(j - 250) * 1e-6;
    double y = (double)(i - 250) * 1e-6;
    double r2 = x * x + y * y;
    double inc_d = exp(-r2 / (2.0 * 1.5e-4 * 1.5e-4));
    double c1 = fmod(M_PI / (5.32e-7 * 0.1) * r2, 2.0 * M_PI);
    float inc = (float)inc_d;
    float b1r = (float)cos(c1);
    float b1i = (float)(-sin(c1));
    float ph = phase[idx];
    float sp, cp;
    sincosf(ph, &sp, &cp);
    float ar = inc * cp, ai = inc * sp;
    field[idx] = make_float2(ar * b1r - ai * b1i, ar * b1i + ai * b1r);

    double fy = (double)((i < 250) ? i : i - 500) * 2000.0;
    double fx = (double)((j < 250) ? j : j - 500) * 2000.0;
    double a = 5.32e-7 * fx;
    double b = 5.32e-7 * fy;
    double g = 1.0 - a * a - b * b;
    g = (g > 0.0) ? sqrt(g) : 0.0;
    float Kf = (float)(2.0 * M_PI * 1.0 / 5.32e-7);
    kgamma[idx] = Kf * (float)g;
}

// ---------------------------------------------------------------------------
// 500-pt forward DFT via Cooley-Tukey 20x25 (see r6). Two variants:
//  rows: reads field row y contiguous, writes R1T[k][y] (transposed store —
//        scatter on the write side, no read-latency stall)
//  cols: reads R1T[kx][y] contiguous, writes EfT[kx][ky] contiguous.
// ---------------------------------------------------------------------------
__device__ __forceinline__ void ct_dft_stages(const float2* xs, const float2* tts,
                                              float2* S, int t,
                                              float2* out1, float2* out2, int* kout) {
    // stage 1: t < 250 -> (b = t%25, d = t/25 in [0,10)), d+10 via parity
    if (t < 250) {
        int d = t / 25;
        int b = t % 25;
        float2 st = tts[(25 * d) % NN];
        float wr = 1.f, wi = 0.f;
        float Er = 0.f, Ei = 0.f, Or_ = 0.f, Oi = 0.f;
#pragma unroll
        for (int a = 0; a < 20; a += 2) {
            float2 x0 = xs[25 * a + b];
            Er += x0.x * wr - x0.y * wi;
            Ei += x0.x * wi + x0.y * wr;
            float nr = wr * st.x - wi * st.y;
            float ni = wr * st.y + wi * st.x;
            float2 x1 = xs[25 * (a + 1) + b];
            Or_ += x1.x * nr - x1.y * ni;
            Oi  += x1.x * ni + x1.y * nr;
            wr = nr * st.x - ni * st.y;
            wi = nr * st.y + ni * st.x;
        }
        S[b * 21 + d]      = make_float2(Er + Or_, Ei + Oi);
        S[b * 21 + d + 10] = make_float2(Er - Or_, Ei - Oi);
    }
    __syncthreads();
    // stage 2: t < 250 -> outputs k = t and k+250
    if (t < 250) {
        int k = t;
        int d1 = k % 20;
        int d2 = (d1 + 10) % 20;
        float2 s1 = tts[k];
        float wr = 1.f, wi = 0.f;
        float a1r = 0.f, a1i = 0.f, a2r = 0.f, a2i = 0.f;
#pragma unroll
        for (int b = 0; b < 25; ++b) {
            float2 u1 = S[b * 21 + d1];
            float2 u2 = S[b * 21 + d2];
            a1r += u1.x * wr - u1.y * wi;
            a1i += u1.x * wi + u1.y * wr;
            float sgnb = (b & 1) ? -1.f : 1.f;
            float w2r = sgnb * wr, w2i = sgnb * wi;
            a2r += u2.x * w2r - u2.y * w2i;
            a2i += u2.x * w2i + u2.y * w2r;
            float nr = wr * s1.x - wi * s1.y;
            wi = wr * s1.y + wi * s1.x;
            wr = nr;
        }
        *out1 = make_float2(a1r, a1i);
        *out2 = make_float2(a2r, a2i);
        *kout = k;
    }
}

__global__ void k_dft_rows(const float2* __restrict__ src, float2* __restrict__ dst,
                           const float2* __restrict__ tw) {
    __shared__ __align__(16) float2 xs[NN];
    __shared__ float2 tts[NN];
    __shared__ float2 S[25 * 21];
    int line = blockIdx.x;                 // y
    const float2* s = src + (size_t)line * NN;
    int t = threadIdx.x;
    for (int n = t; n < NN; n += 256) {
        xs[n] = s[n];
        float2 tt = tw[n];
        tts[n] = make_float2(tt.x, -tt.y);   // forward
    }
    __syncthreads();
    float2 o1, o2; int k;
    ct_dft_stages(xs, tts, S, t, &o1, &o2, &k);
    if (t < 250) {
        dst[(size_t)k * NN + line] = o1;           // R1T[k][y]
        dst[(size_t)(k + 250) * NN + line] = o2;
    }
}

__global__ void k_dft_cols(const float2* __restrict__ src, float2* __restrict__ dst,
                           const float2* __restrict__ tw) {
    __shared__ __align__(16) float2 xs[NN];
    __shared__ float2 tts[NN];
    __shared__ float2 S[25 * 21];
    int line = blockIdx.x;                 // kx
    const float2* s = src + (size_t)line * NN;     // R1T row kx, contiguous
    int t = threadIdx.x;
    for (int n = t; n < NN; n += 256) {
        xs[n] = s[n];
        float2 tt = tw[n];
        tts[n] = make_float2(tt.x, -tt.y);
    }
    __syncthreads();
    float2 o1, o2; int k;
    ct_dft_stages(xs, tts, S, t, &o1, &o2, &k);
    if (t < 250) {
        float2* dp = dst + (size_t)line * NN;      // EfT[kx][*], contiguous
        dp[k] = o1;
        dp[k + 250] = o2;
    }
}

// ---------------------------------------------------------------------------
// B1 (v7 structure, roles u<->v swapped): block = (v, zhalf), reads EfT row v
// (contiguous) + kgamma row v (= column by exact symmetry), modulates by H,
// partial DFT over u for crop rows r = 235..265 with parity fold.
//   part[z][r][v] = sum_u EfT[v,u]*e^{i*kg[v,u]*z} * e^{+2pi*i*u*r/500}
// ---------------------------------------------------------------------------
__global__ void __launch_bounds__(256, 5)
k_prop_rows(const float2* __restrict__ EfT,
            const float* __restrict__ kgamma,
            const float* __restrict__ zs,
            float2* __restrict__ part) {
    __shared__ __align__(16) float2 Ys[8][NN];   // 32000 B
    int v = blockIdx.x;
    int zhalf = blockIdx.y;
    int t = threadIdx.x;
    int w = t >> 6;             // wave id 0..3 -> z rows 2w, 2w+1
    int lane = t & 63;
    int co = lane >> 3;         // 0..7 : r-quad index
    int vs = lane & 7;          // 0..7 : u-segment
    int r0 = 235 + 4 * co;      // r = r0..r0+3 (co=7,rl=3 -> 266 dummy)

    const float2* erow = EfT + (size_t)v * NN;
    const float* grow = kgamma + (size_t)v * NN;

    float w0r[4], w0i[4], s1r[4], s1i[4], str[4], sti[4];
#pragma unroll
    for (int rl = 0; rl < 4; ++rl) {
        int r = r0 + rl;
        float th0 = (TWO_PI_F / NN) * (float)((2 * vs * r) % NN);
        sincosf(th0, &w0i[rl], &w0r[rl]);
        float th1 = (TWO_PI_F / NN) * (float)(r % NN);
        sincosf(th1, &s1i[rl], &s1r[rl]);
        float ths = (TWO_PI_F / NN) * (float)((16 * r) % NN);
        sincosf(ths, &sti[rl], &str[rl]);
    }

    for (int g = 0; g < 4; ++g) {
        int zbase = zhalf * 32 + g * 8;
        float zv[8];
#pragma unroll
        for (int zi = 0; zi < 8; ++zi) zv[zi] = zs[zbase + zi];
        for (int u = t; u < NN; u += 256) {
            float2 e = erow[u];
            float kg = grow[u];
#pragma unroll
            for (int zi = 0; zi < 8; ++zi) {
                float s, cc;
                fast_sincos_red(kg * zv[zi], &s, &cc);
                Ys[zi][u] = make_float2(e.x * cc - e.y * s, e.x * s + e.y * cc);
            }
        }
        __syncthreads();

        float wr[4], wi[4];
#pragma unroll
        for (int rl = 0; rl < 4; ++rl) { wr[rl] = w0r[rl]; wi[rl] = w0i[rl]; }
        float accr[4][2], acci[4][2];
#pragma unroll
        for (int rl = 0; rl < 4; ++rl)
#pragma unroll
            for (int j = 0; j < 2; ++j) { accr[rl][j] = 0.f; acci[rl][j] = 0.f; }

        for (int pc = vs; pc < 125; pc += 8) {   // pair-columns: u=2pc, 2pc+1
            int u = 2 * pc;
            float4 x0a = *(const float4*)&Ys[2 * w + 0][u];
            float4 x0b = *(const float4*)&Ys[2 * w + 0][u + 250];
            float4 x1a = *(const float4*)&Ys[2 * w + 1][u];
            float4 x1b = *(const float4*)&Ys[2 * w + 1][u + 250];
            float e0vr = x0a.x + x0b.x, e0vi = x0a.y + x0b.y;
            float o0vr = x0a.x - x0b.x, o0vi = x0a.y - x0b.y;
            float e0wr_ = x0a.z + x0b.z, e0wi_ = x0a.w + x0b.w;
            float o0wr_ = x0a.z - x0b.z, o0wi_ = x0a.w - x0b.w;
            float e1vr = x1a.x + x1b.x, e1vi = x1a.y + x1b.y;
            float o1vr = x1a.x - x1b.x, o1vi = x1a.y - x1b.y;
            float e1wr_ = x1a.z + x1b.z, e1wi_ = x1a.w + x1b.w;
            float o1wr_ = x1a.z - x1b.z, o1wi_ = x1a.w - x1b.w;
#pragma unroll
            for (int rl = 0; rl < 4; ++rl) {
                float ar = wr[rl], ai = wi[rl];
                float br = ar * s1r[rl] - ai * s1i[rl];
                float bi = ar * s1i[rl] + ai * s1r[rl];
                if ((rl & 1) == 0) {   // r odd -> odd-parity sums
                    accr[rl][0] += o0vr * ar - o0vi * ai + o0wr_ * br - o0wi_ * bi;
                    acci[rl][0] += o0vr * ai + o0vi * ar + o0wr_ * bi + o0wi_ * br;
                    accr[rl][1] += o1vr * ar - o1vi * ai + o1wr_ * br - o1wi_ * bi;
                    acci[rl][1] += o1vr * ai + o1vi * ar + o1wr_ * bi + o1wi_ * br;
                } else {               // r even -> even-parity sums
                    accr[rl][0] += e0vr * ar - e0vi * ai + e0wr_ * br - e0wi_ * bi;
                    acci[rl][0] += e0vr * ai + e0vi * ar + e0wr_ * bi + e0wi_ * br;
                    accr[rl][1] += e1vr * ar - e1vi * ai + e1wr_ * br - e1wi_ * bi;
                    acci[rl][1] += e1vr * ai + e1vi * ar + e1wr_ * bi + e1wi_ * br;
                }
                float nwr = ar * str[rl] - ai * sti[rl];
                wi[rl] = ar * sti[rl] + ai * str[rl];
                wr[rl] = nwr;
            }
        }

#pragma unroll
        for (int rl = 0; rl < 4; ++rl)
#pragma unroll
            for (int j = 0; j < 2; ++j) {
#pragma unroll
                for (int m = 1; m < 8; m <<= 1) {
                    accr[rl][j] += __shfl_xor(accr[rl][j], m);
                    acci[rl][j] += __shfl_xor(acci[rl][j], m);
                }
            }
        if (vs == 0) {
#pragma unroll
            for (int rl = 0; rl < 4; ++rl) {
                int r = r0 + rl;
                if (r <= 265) {
#pragma unroll
                    for (int j = 0; j < 2; ++j) {
                        int z = zbase + 2 * w + j;
                        part[((size_t)z * PW + (r - 235)) * NN + v] =
                            make_float2(accr[rl][j], acci[rl][j]);
                    }
                }
            }
        }
        __syncthreads();
    }
}

// ---------------------------------------------------------------------------
// B2: per (r,z): psf[z][r][c] = |1/500^2 * sum_v part[z][r][v] W^{vc}|^2,
// c = 235..265. Contiguous psf writes + per-block sum into psf_sums[z].
// ---------------------------------------------------------------------------
__global__ void k_prop_cols(const float2* __restrict__ part,
                            float* __restrict__ psf,
                            float* __restrict__ psf_sums) {
    __shared__ float2 X[NN];
    __shared__ float sred[PW];
    int r = blockIdx.x;    // 31
    int z = blockIdx.y;    // 64
    int t = threadIdx.x;
    const float2* col = part + ((size_t)z * PW + r) * NN;
    for (int v = t; v < NN; v += 256) X[v] = col[v];
    __syncthreads();
    if (t < PW * 8) {
        int ci = t >> 3, seg = t & 7;
        int c = 235 + ci;
        float wr, wi, sr, si;
        {
            float th0 = (TWO_PI_F / NN) * (float)((seg * c) % NN);
            sincosf(th0, &wi, &wr);
            float ths = (TWO_PI_F / NN) * (float)((8 * c) % NN);
            sincosf(ths, &si, &sr);
        }
        float ar = 0.f, ai = 0.f;
        for (int v = seg; v < NN; v += 8) {
            float2 xv = X[v];
            ar += xv.x * wr - xv.y * wi;
            ai += xv.x * wi + xv.y * wr;
            float nwr = wr * sr - wi * si;
            wi = wr * si + wi * sr;
            wr = nwr;
        }
#pragma unroll
        for (int m = 1; m < 8; m <<= 1) {
            ar += __shfl_xor(ar, m);
            ai += __shfl_xor(ai, m);
        }
        if (seg == 0 && ci < PW) {
            const float inv = 1.0f / 250000.0f;
            float re = ar * inv, im = ai * inv;
            float val = re * re + im * im;
            psf[(size_t)z * (PW * PW) + r * PW + ci] = val;
            sred[ci] = val;
        }
    }
    __syncthreads();
    if (t == 0) {
        float s = 0.f;
#pragma unroll
        for (int i = 0; i < PW; ++i) s += sred[i];
        atomicAdd(&psf_sums[z], s);
    }
}

// ---------------------------------------------------------------------------
// Scatter-add PSFs onto canvases, scale computed inline from psf_sums.
// ---------------------------------------------------------------------------
__global__ void k_scatter(const float* __restrict__ psf,
                          const float* __restrict__ psf_sums,
                          const int* __restrict__ xyz,
                          float* __restrict__ canvas) {
    int e = blockIdx.x;
    int b = blockIdx.y;
    int r0 = xyz[(b * NE + e) * 2 + 0] - RR;
    int c0 = xyz[(b * NE + e) * 2 + 1] - RR;
    float sc = 1.0e6f / (psf_sums[e] + 1e-12f);
    float* cb = canvas + (size_t)b * (CAN * CAN);
    for (int p = threadIdx.x; p < PW * PW; p += blockDim.x) {
        int i = p / PW, j = p % PW;
        atomicAdd(cb + (r0 + i) * CAN + (c0 + j), psf[e * PW * PW + p] * sc);
    }
}

// ---------------------------------------------------------------------------
// 7x7 blur (zero-padded) + sensor noise chain, 2D-tiled via LDS.
// Block (32,8) -> 32x8 outputs; tile 14x38 canvas floats staged once.
// ---------------------------------------------------------------------------
__global__ void k_final(const float* __restrict__ canvas,
                        const float* __restrict__ kern,
                        const float* __restrict__ eps_dark,
                        const float* __restrict__ eps_photon,
                        const float* __restrict__ eps_read,
                        float* __restrict__ out) {
    __shared__ float kk[49];
    __shared__ float tile[14][40];
    int b = blockIdx.z;
    int tx = threadIdx.x, ty = threadIdx.y;
    int t = ty * 32 + tx;
    int j0 = blockIdx.x * 32, i0 = blockIdx.y * 8;
    if (t < 49) kk[t] = kern[t];
    const float* cb = canvas + (size_t)b * (CAN * CAN);
    for (int p = t; p < 14 * 38; p += 256) {
        int rr = p / 38, cc = p % 38;
        int gi = i0 + rr - 2, gj = j0 + cc - 2;
        tile[rr][cc] = (gi >= 0 && gi < CAN && gj >= 0 && gj < CAN)
                           ? cb[gi * CAN + gj] : 0.f;
    }
    __syncthreads();
    int i = i0 + ty, j = j0 + tx;
    if (i >= OHW || j >= OHW) return;
    float acc = 0.f;
#pragma unroll
    for (int a = 0; a < 7; ++a)
#pragma unroll
        for (int q = 0; q < 7; ++q)
            acc += tile[ty + a][tx + q] * kk[a * 7 + q];
    int idx = b * (OHW * OHW) + i * OHW + j;
    float sig = acc * 0.9f;
    float dark = 0.005f + eps_dark[idx] * sqrtf(0.005f);
    float total = fmaxf(sig + dark, 0.0f);
    float noisy = total + eps_photon[idx] * sqrtf(fmaxf(total, 1e-12f));
    float elec = noisy + eps_read[idx] * 1.6f;
    float adu = fminf(fmaxf(elec * 2.0f, 0.0f), 65535.0f);
    float v = (adu <= 10.0f) ? 1.0f : fminf(adu, 4.0e9f);
    out[idx] = v / 4.0e9f;
}

// ---------------------------------------------------------------------------
extern "C" void kernel_launch(void* const* d_in, const int* in_sizes, int n_in,
                              void* d_out, int out_size, void* d_ws, size_t ws_size,
                              hipStream_t stream) {
    const float* phase    = (const float*)d_in[0];
    const float* zs       = (const float*)d_in[1];
    const int*   xyz      = (const int*)d_in[2];
    const float* std_u    = (const float*)d_in[3];
    const float* epsd     = (const float*)d_in[4];
    const float* epsp     = (const float*)d_in[5];
    const float* epsr     = (const float*)d_in[6];
    float* out = (float*)d_out;

    char* ws = (char*)d_ws;
    size_t off = 0;
    auto alloc = [&](size_t bytes) {
        off = (off + 255) & ~(size_t)255;
        size_t o = off; off += bytes; return o;
    };
    float2* field    = (float2*)(ws + alloc((size_t)NN * NN * 8));
    float*  kgamma   = (float*) (ws + alloc((size_t)NN * NN * 4));
    float2* tw       = (float2*)(ws + alloc((size_t)NN * 8));
    float2* R1T      = (float2*)(ws + alloc((size_t)NN * NN * 8));
    float2* EfT      = (float2*)(ws + alloc((size_t)NN * NN * 8));
    float2* part     = (float2*)(ws + alloc((size_t)NE * PW * NN * 8));
    float*  psf      = (float*) (ws + alloc((size_t)NE * PW * PW * 4));
    float*  psf_sums = (float*) (ws + alloc((size_t)NE * 4));
    float*  kern     = (float*) (ws + alloc((size_t)64 * 4));
    float*  canvas   = (float*) (ws + alloc((size_t)BATCH * CAN * CAN * 4));
    (void)ws_size; (void)n_in; (void)in_sizes; (void)out_size;

    int prep_n = BATCH * CAN * CAN + NE + 49;     // canvas + psf_sums + kern
    k_prep<<<(prep_n + 255) / 256, 256, 0, stream>>>(
        phase, std_u, field, kgamma, tw, kern, canvas, psf_sums);
    // fft2: rows (writes transposed) then cols (fully contiguous)
    k_dft_rows<<<NN, 256, 0, stream>>>(field, R1T, tw);
    k_dft_cols<<<NN, 256, 0, stream>>>(R1T, EfT, tw);
    // partial inverse transforms for the 31x31 crop, all 64 z-planes
    k_prop_rows<<<dim3(NN, 2), 256, 0, stream>>>(EfT, kgamma, zs, part);
    k_prop_cols<<<dim3(PW, NE), 256, 0, stream>>>(part, psf, psf_sums);
    k_scatter<<<dim3(NE, BATCH), 256, 0, stream>>>(psf, psf_sums, xyz, canvas);
    k_final<<<dim3((OHW + 31) / 32, (OHW + 7) / 8, BATCH), dim3(32, 8), 0, stream>>>(
        canvas, kern, epsd, epsp, epsr, out);
}

// Round 10
// 190.821 us; speedup vs baseline: 1.6483x; 1.0369x over previous
//
#include <hip/hip_runtime.h>
#include <math.h>

#define NN 500
#define NE 64
#define BATCH 8
#define RR 15
#define PW 31            // 2R+1
#define CAN 200
#define OHW 198
#define TWO_PI_F 6.28318530717958647692f
// k_setup must cover canvas (320000) + psf_sums (64) + kern (49) AND NN*NN.
#define SETUP_N (BATCH * CAN * CAN + NE + 49)

// Fast accurate sincos for |theta| up to ~1200 rad: Cody-Waite 2-term
// reduction + hardware v_sin/v_cos on the reduced |r| <= pi argument.
__device__ __forceinline__ void fast_sincos_red(float theta, float* s, float* c) {
    const float INV2PI = 0.15915494309189535f;
    const float PI2_HI = 6.28318548202514648f;   // f32(2*pi)
    const float PI2_LO = -1.7484556e-7f;         // 2*pi - PI2_HI
    float n = rintf(theta * INV2PI);
    float r = fmaf(n, -PI2_HI, theta);
    r = fmaf(n, -PI2_LO, r);
    *s = __sinf(r);
    *c = __cosf(r);
}

// ---------------------------------------------------------------------------
// K_setup: K*GAMMA table (f64 sqrt path), 500-pt twiddle table, blur-kernel
// coefficients, canvas+psf_sums zero. GRID MUST COVER SETUP_N (r9 bug: grid
// was NN*NN=250000 < 320113, leaving kern/psf_sums 0xAA-poisoned).
// ---------------------------------------------------------------------------
__global__ void k_setup(const float* __restrict__ std_u,
                        float* __restrict__ kgamma,
                        float2* __restrict__ tw,
                        float* __restrict__ kern,
                        float* __restrict__ canvas,
                        float* __restrict__ psf_sums) {
    int idx = blockIdx.x * blockDim.x + threadIdx.x;
    if (idx < NN) {
        double th = 2.0 * M_PI * (double)idx / (double)NN;
        tw[idx] = make_float2((float)cos(th), (float)sin(th));
    }
    if (idx < BATCH * CAN * CAN) canvas[idx] = 0.f;
    if (idx >= BATCH * CAN * CAN && idx < BATCH * CAN * CAN + NE)
        psf_sums[idx - BATCH * CAN * CAN] = 0.f;
    if (idx >= BATCH * CAN * CAN + NE && idx < SETUP_N) {
        int t = idx - (BATCH * CAN * CAN + NE);
        float stdv = 0.8f + 0.4f * std_u[0];
        float s2 = stdv * stdv;
        int a = t / 7 - 3, b = t % 7 - 3;
        float g = (float)exp(-0.5 * (double)(a * a + b * b));
        kern[t] = (1.0f / (2.0f * (float)M_PI * s2)) * powf(g, 1.0f / s2);
    }
    if (idx >= NN * NN) return;
    int i = idx / NN, j = idx % NN;
    double fy = (double)((i < 250) ? i : i - 500) * 2000.0;
    double fx = (double)((j < 250) ? j : j - 500) * 2000.0;
    double a = 5.32e-7 * fx;
    double b = 5.32e-7 * fy;
    double g = 1.0 - a * a - b * b;
    g = (g > 0.0) ? sqrt(g) : 0.0;
    float Kf = (float)(2.0 * M_PI * 1.0 / 5.32e-7);
    kgamma[idx] = Kf * (float)g;
}

// ---------------------------------------------------------------------------
// 500-pt forward DFT via Cooley-Tukey 20x25. Shared stages helper.
// ---------------------------------------------------------------------------
__device__ __forceinline__ void ct_dft_stages(const float2* xs, const float2* tts,
                                              float2* S, int t,
                                              float2* out1, float2* out2, int* kout) {
    if (t < 250) {
        int d = t / 25;
        int b = t % 25;
        float2 st = tts[(25 * d) % NN];
        float wr = 1.f, wi = 0.f;
        float Er = 0.f, Ei = 0.f, Or_ = 0.f, Oi = 0.f;
#pragma unroll
        for (int a = 0; a < 20; a += 2) {
            float2 x0 = xs[25 * a + b];
            Er += x0.x * wr - x0.y * wi;
            Ei += x0.x * wi + x0.y * wr;
            float nr = wr * st.x - wi * st.y;
            float ni = wr * st.y + wi * st.x;
            float2 x1 = xs[25 * (a + 1) + b];
            Or_ += x1.x * nr - x1.y * ni;
            Oi  += x1.x * ni + x1.y * nr;
            wr = nr * st.x - ni * st.y;
            wi = nr * st.y + ni * st.x;
        }
        S[b * 21 + d]      = make_float2(Er + Or_, Ei + Oi);
        S[b * 21 + d + 10] = make_float2(Er - Or_, Ei - Oi);
    }
    __syncthreads();
    if (t < 250) {
        int k = t;
        int d1 = k % 20;
        int d2 = (d1 + 10) % 20;
        float2 s1 = tts[k];
        float wr = 1.f, wi = 0.f;
        float a1r = 0.f, a1i = 0.f, a2r = 0.f, a2i = 0.f;
#pragma unroll
        for (int b = 0; b < 25; ++b) {
            float2 u1 = S[b * 21 + d1];
            float2 u2 = S[b * 21 + d2];
            a1r += u1.x * wr - u1.y * wi;
            a1i += u1.x * wi + u1.y * wr;
            float sgnb = (b & 1) ? -1.f : 1.f;
            float w2r = sgnb * wr, w2i = sgnb * wi;
            a2r += u2.x * w2r - u2.y * w2i;
            a2i += u2.x * w2i + u2.y * w2r;
            float nr = wr * s1.x - wi * s1.y;
            wi = wr * s1.y + wi * s1.x;
            wr = nr;
        }
        *out1 = make_float2(a1r, a1i);
        *out2 = make_float2(a2r, a2i);
        *kout = k;
    }
}

// k_dft_rows: fused pupil-field generation (f32) + row DFT; writes R1T[k][y].
//   field[i][j] = exp(-r2/(2 FWHC^2)) * e^{i phase} * e^{-i C1},
//   C1 = (pi/(WL FL)) r2 (<= 7.4 rad, __sinf/__cosf handle directly)
__global__ void k_dft_rows(const float* __restrict__ phase, float2* __restrict__ dst,
                           const float2* __restrict__ tw) {
    __shared__ __align__(16) float2 xs[NN];
    __shared__ float2 tts[NN];
    __shared__ float2 S[25 * 21];
    int line = blockIdx.x;                 // y index i
    int t = threadIdx.x;
    const float INV2SIG = 2.2222222e7f;              // 1/(2*(1.5e-4)^2)
    const float C1M = (float)(M_PI / 5.32e-8);       // pi/(WL*FL)
    float y = (float)(line - 250) * 1e-6f;
    float y2 = y * y;
    const float* prow = phase + (size_t)line * NN;
    for (int n = t; n < NN; n += 256) {
        float x = (float)(n - 250) * 1e-6f;
        float r2 = x * x + y2;
        float inc = __expf(-r2 * INV2SIG);
        float c1 = C1M * r2;
        float b1r = __cosf(c1), b1i = -__sinf(c1);
        float ph = prow[n];
        float sp = __sinf(ph), cp = __cosf(ph);
        float ar = inc * cp, ai = inc * sp;
        xs[n] = make_float2(ar * b1r - ai * b1i, ar * b1i + ai * b1r);
        float2 tt = tw[n];
        tts[n] = make_float2(tt.x, -tt.y);   // forward
    }
    __syncthreads();
    float2 o1, o2; int k;
    ct_dft_stages(xs, tts, S, t, &o1, &o2, &k);
    if (t < 250) {
        dst[(size_t)k * NN + line] = o1;           // R1T[k][y]
        dst[(size_t)(k + 250) * NN + line] = o2;
    }
}

__global__ void k_dft_cols(const float2* __restrict__ src, float2* __restrict__ dst,
                           const float2* __restrict__ tw) {
    __shared__ __align__(16) float2 xs[NN];
    __shared__ float2 tts[NN];
    __shared__ float2 S[25 * 21];
    int line = blockIdx.x;                 // kx
    const float2* s = src + (size_t)line * NN;     // R1T row kx, contiguous
    int t = threadIdx.x;
    for (int n = t; n < NN; n += 256) {
        xs[n] = s[n];
        float2 tt = tw[n];
        tts[n] = make_float2(tt.x, -tt.y);
    }
    __syncthreads();
    float2 o1, o2; int k;
    ct_dft_stages(xs, tts, S, t, &o1, &o2, &k);
    if (t < 250) {
        float2* dp = dst + (size_t)line * NN;      // EfT[kx][*], contiguous
        dp[k] = o1;
        dp[k + 250] = o2;
    }
}

// ---------------------------------------------------------------------------
// B1 v9: (a) erow/grow prefetched to registers ONCE (reused by all 4 passes),
// (b) parity fold precomputed in modulate: Yeo[z][u] = {e.re,e.im,o.re,o.im},
// e = Y[u]+Y[u+250], o = Y[u]-Y[u+250] (u<250).
//   part[z][r][v] = sum_u EfT[v,u]*e^{i*kg[v,u]*z} * e^{+2pi*i*u*r/500}
// ---------------------------------------------------------------------------
__global__ void __launch_bounds__(256, 5)
k_prop_rows(const float2* __restrict__ EfT,
            const float* __restrict__ kgamma,
            const float* __restrict__ zs,
            float2* __restrict__ part) {
    __shared__ __align__(16) float4 Yeo[8][250];   // 32000 B
    int v = blockIdx.x;
    int zhalf = blockIdx.y;
    int t = threadIdx.x;
    int w = t >> 6;             // wave id 0..3 -> z rows 2w, 2w+1
    int lane = t & 63;
    int co = lane >> 3;         // 0..7 : r-quad index
    int vs = lane & 7;          // 0..7 : u-segment
    int r0 = 235 + 4 * co;      // r = r0..r0+3 (co=7,rl=3 -> 266 dummy)

    const float2* erow = EfT + (size_t)v * NN;
    const float* grow = kgamma + (size_t)v * NN;

    // prefetch the whole row pair once; reused across all 4 passes
    float2 eA = make_float2(0.f, 0.f), eB = eA;
    float kgA = 0.f, kgB = 0.f;
    if (t < 250) {
        eA = erow[t];   eB = erow[t + 250];
        kgA = grow[t];  kgB = grow[t + 250];
    }

    float w0r[4], w0i[4], s1r[4], s1i[4], str[4], sti[4];
#pragma unroll
    for (int rl = 0; rl < 4; ++rl) {
        int r = r0 + rl;
        float th0 = (TWO_PI_F / NN) * (float)((2 * vs * r) % NN);
        sincosf(th0, &w0i[rl], &w0r[rl]);
        float th1 = (TWO_PI_F / NN) * (float)(r % NN);
        sincosf(th1, &s1i[rl], &s1r[rl]);
        float ths = (TWO_PI_F / NN) * (float)((16 * r) % NN);
        sincosf(ths, &sti[rl], &str[rl]);
    }

    for (int g = 0; g < 4; ++g) {
        int zbase = zhalf * 32 + g * 8;
        float zv[8];
#pragma unroll
        for (int zi = 0; zi < 8; ++zi) zv[zi] = zs[zbase + zi];
        // modulate + parity fold, all from registers
        if (t < 250) {
#pragma unroll
            for (int zi = 0; zi < 8; ++zi) {
                float sA, cA, sB, cB;
                fast_sincos_red(kgA * zv[zi], &sA, &cA);
                fast_sincos_red(kgB * zv[zi], &sB, &cB);
                float y0r = eA.x * cA - eA.y * sA, y0i = eA.x * sA + eA.y * cA;
                float y1r = eB.x * cB - eB.y * sB, y1i = eB.x * sB + eB.y * cB;
                Yeo[zi][t] = make_float4(y0r + y1r, y0i + y1i,
                                         y0r - y1r, y0i - y1i);
            }
        }
        __syncthreads();

        float wr[4], wi[4];
#pragma unroll
        for (int rl = 0; rl < 4; ++rl) { wr[rl] = w0r[rl]; wi[rl] = w0i[rl]; }
        float accr[4][2], acci[4][2];
#pragma unroll
        for (int rl = 0; rl < 4; ++rl)
#pragma unroll
            for (int j = 0; j < 2; ++j) { accr[rl][j] = 0.f; acci[rl][j] = 0.f; }

        for (int pc = vs; pc < 125; pc += 8) {   // columns u=2pc, 2pc+1
            int u = 2 * pc;
            float4 y0a = Yeo[2 * w + 0][u];      // z row 0: col u  {e,o}
            float4 y0b = Yeo[2 * w + 0][u + 1];  // z row 0: col u+1
            float4 y1a = Yeo[2 * w + 1][u];
            float4 y1b = Yeo[2 * w + 1][u + 1];
#pragma unroll
            for (int rl = 0; rl < 4; ++rl) {
                float ar = wr[rl], ai = wi[rl];              // twiddle at u
                float br = ar * s1r[rl] - ai * s1i[rl];      // twiddle at u+1
                float bi = ar * s1i[rl] + ai * s1r[rl];
                if ((rl & 1) == 0) {   // r odd -> odd-parity (.z,.w)
                    accr[rl][0] += y0a.z * ar - y0a.w * ai + y0b.z * br - y0b.w * bi;
                    acci[rl][0] += y0a.z * ai + y0a.w * ar + y0b.z * bi + y0b.w * br;
                    accr[rl][1] += y1a.z * ar - y1a.w * ai + y1b.z * br - y1b.w * bi;
                    acci[rl][1] += y1a.z * ai + y1a.w * ar + y1b.z * bi + y1b.w * br;
                } else {               // r even -> even-parity (.x,.y)
                    accr[rl][0] += y0a.x * ar - y0a.y * ai + y0b.x * br - y0b.y * bi;
                    acci[rl][0] += y0a.x * ai + y0a.y * ar + y0b.x * bi + y0b.y * br;
                    accr[rl][1] += y1a.x * ar - y1a.y * ai + y1b.x * br - y1b.y * bi;
                    acci[rl][1] += y1a.x * ai + y1a.y * ar + y1b.x * bi + y1b.y * br;
                }
                float nwr = ar * str[rl] - ai * sti[rl];
                wi[rl] = ar * sti[rl] + ai * str[rl];
                wr[rl] = nwr;
            }
        }

#pragma unroll
        for (int rl = 0; rl < 4; ++rl)
#pragma unroll
            for (int j = 0; j < 2; ++j) {
#pragma unroll
                for (int m = 1; m < 8; m <<= 1) {
                    accr[rl][j] += __shfl_xor(accr[rl][j], m);
                    acci[rl][j] += __shfl_xor(acci[rl][j], m);
                }
            }
        if (vs == 0) {
#pragma unroll
            for (int rl = 0; rl < 4; ++rl) {
                int r = r0 + rl;
                if (r <= 265) {
#pragma unroll
                    for (int j = 0; j < 2; ++j) {
                        int z = zbase + 2 * w + j;
                        part[((size_t)z * PW + (r - 235)) * NN + v] =
                            make_float2(accr[rl][j], acci[rl][j]);
                    }
                }
            }
        }
        __syncthreads();
    }
}

// ---------------------------------------------------------------------------
// B2: per (r,z): psf[z][r][c] = |1/500^2 * sum_v part[z][r][v] W^{vc}|^2,
// c = 235..265. Contiguous psf writes + per-block sum into psf_sums[z].
// ---------------------------------------------------------------------------
__global__ void k_prop_cols(const float2* __restrict__ part,
                            float* __restrict__ psf,
                            float* __restrict__ psf_sums) {
    __shared__ float2 X[NN];
    __shared__ float sred[PW];
    int r = blockIdx.x;    // 31
    int z = blockIdx.y;    // 64
    int t = threadIdx.x;
    const float2* col = part + ((size_t)z * PW + r) * NN;
    for (int v = t; v < NN; v += 256) X[v] = col[v];
    __syncthreads();
    if (t < PW * 8) {
        int ci = t >> 3, seg = t & 7;
        int c = 235 + ci;
        float wr, wi, sr, si;
        {
            float th0 = (TWO_PI_F / NN) * (float)((seg * c) % NN);
            sincosf(th0, &wi, &wr);
            float ths = (TWO_PI_F / NN) * (float)((8 * c) % NN);
            sincosf(ths, &si, &sr);
        }
        float ar = 0.f, ai = 0.f;
        for (int v = seg; v < NN; v += 8) {
            float2 xv = X[v];
            ar += xv.x * wr - xv.y * wi;
            ai += xv.x * wi + xv.y * wr;
            float nwr = wr * sr - wi * si;
            wi = wr * si + wi * sr;
            wr = nwr;
        }
#pragma unroll
        for (int m = 1; m < 8; m <<= 1) {
            ar += __shfl_xor(ar, m);
            ai += __shfl_xor(ai, m);
        }
        if (seg == 0 && ci < PW) {
            const float inv = 1.0f / 250000.0f;
            float re = ar * inv, im = ai * inv;
            float val = re * re + im * im;
            psf[(size_t)z * (PW * PW) + r * PW + ci] = val;
            sred[ci] = val;
        }
    }
    __syncthreads();
    if (t == 0) {
        float s = 0.f;
#pragma unroll
        for (int i = 0; i < PW; ++i) s += sred[i];
        atomicAdd(&psf_sums[z], s);
    }
}

// ---------------------------------------------------------------------------
__global__ void k_scatter(const float* __restrict__ psf,
                          const float* __restrict__ psf_sums,
                          const int* __restrict__ xyz,
                          float* __restrict__ canvas) {
    int e = blockIdx.x;
    int b = blockIdx.y;
    int r0 = xyz[(b * NE + e) * 2 + 0] - RR;
    int c0 = xyz[(b * NE + e) * 2 + 1] - RR;
    float sc = 1.0e6f / (psf_sums[e] + 1e-12f);
    float* cb = canvas + (size_t)b * (CAN * CAN);
    for (int p = threadIdx.x; p < PW * PW; p += blockDim.x) {
        int i = p / PW, j = p % PW;
        atomicAdd(cb + (r0 + i) * CAN + (c0 + j), psf[e * PW * PW + p] * sc);
    }
}

// ---------------------------------------------------------------------------
__global__ void k_final(const float* __restrict__ canvas,
                        const float* __restrict__ kern,
                        const float* __restrict__ eps_dark,
                        const float* __restrict__ eps_photon,
                        const float* __restrict__ eps_read,
                        float* __restrict__ out) {
    __shared__ float kk[49];
    __shared__ float tile[14][40];
    int b = blockIdx.z;
    int tx = threadIdx.x, ty = threadIdx.y;
    int t = ty * 32 + tx;
    int j0 = blockIdx.x * 32, i0 = blockIdx.y * 8;
    if (t < 49) kk[t] = kern[t];
    const float* cb = canvas + (size_t)b * (CAN * CAN);
    for (int p = t; p < 14 * 38; p += 256) {
        int rr = p / 38, cc = p % 38;
        int gi = i0 + rr - 2, gj = j0 + cc - 2;
        tile[rr][cc] = (gi >= 0 && gi < CAN && gj >= 0 && gj < CAN)
                           ? cb[gi * CAN + gj] : 0.f;
    }
    __syncthreads();
    int i = i0 + ty, j = j0 + tx;
    if (i >= OHW || j >= OHW) return;
    float acc = 0.f;
#pragma unroll
    for (int a = 0; a < 7; ++a)
#pragma unroll
        for (int q = 0; q < 7; ++q)
            acc += tile[ty + a][tx + q] * kk[a * 7 + q];
    int idx = b * (OHW * OHW) + i * OHW + j;
    float sig = acc * 0.9f;
    float dark = 0.005f + eps_dark[idx] * sqrtf(0.005f);
    float total = fmaxf(sig + dark, 0.0f);
    float noisy = total + eps_photon[idx] * sqrtf(fmaxf(total, 1e-12f));
    float elec = noisy + eps_read[idx] * 1.6f;
    float adu = fminf(fmaxf(elec * 2.0f, 0.0f), 65535.0f);
    float v = (adu <= 10.0f) ? 1.0f : fminf(adu, 4.0e9f);
    out[idx] = v / 4.0e9f;
}

// ---------------------------------------------------------------------------
extern "C" void kernel_launch(void* const* d_in, const int* in_sizes, int n_in,
                              void* d_out, int out_size, void* d_ws, size_t ws_size,
                              hipStream_t stream) {
    const float* phase    = (const float*)d_in[0];
    const float* zs       = (const float*)d_in[1];
    const int*   xyz      = (const int*)d_in[2];
    const float* std_u    = (const float*)d_in[3];
    const float* epsd     = (const float*)d_in[4];
    const float* epsp     = (const float*)d_in[5];
    const float* epsr     = (const float*)d_in[6];
    float* out = (float*)d_out;

    char* ws = (char*)d_ws;
    size_t off = 0;
    auto alloc = [&](size_t bytes) {
        off = (off + 255) & ~(size_t)255;
        size_t o = off; off += bytes; return o;
    };
    float*  kgamma   = (float*) (ws + alloc((size_t)NN * NN * 4));
    float2* tw       = (float2*)(ws + alloc((size_t)NN * 8));
    float2* R1T      = (float2*)(ws + alloc((size_t)NN * NN * 8));
    float2* EfT      = (float2*)(ws + alloc((size_t)NN * NN * 8));
    float2* part     = (float2*)(ws + alloc((size_t)NE * PW * NN * 8));
    float*  psf      = (float*) (ws + alloc((size_t)NE * PW * PW * 4));
    float*  psf_sums = (float*) (ws + alloc((size_t)NE * 4));
    float*  kern     = (float*) (ws + alloc((size_t)64 * 4));
    float*  canvas   = (float*) (ws + alloc((size_t)BATCH * CAN * CAN * 4));
    (void)ws_size; (void)n_in; (void)in_sizes; (void)out_size;

    // grid covers max(NN*NN, SETUP_N) = SETUP_N = 320113 (r9 bug fix)
    k_setup<<<(SETUP_N + 255) / 256, 256, 0, stream>>>(
        std_u, kgamma, tw, kern, canvas, psf_sums);
    // fft2: rows (fused field gen, writes transposed) then cols (contiguous)
    k_dft_rows<<<NN, 256, 0, stream>>>(phase, R1T, tw);
    k_dft_cols<<<NN, 256, 0, stream>>>(R1T, EfT, tw);
    // partial inverse transforms for the 31x31 crop, all 64 z-planes
    k_prop_rows<<<dim3(NN, 2), 256, 0, stream>>>(EfT, kgamma, zs, part);
    k_prop_cols<<<dim3(PW, NE), 256, 0, stream>>>(part, psf, psf_sums);
    k_scatter<<<dim3(NE, BATCH), 256, 0, stream>>>(psf, psf_sums, xyz, canvas);
    k_final<<<dim3((OHW + 31) / 32, (OHW + 7) / 8, BATCH), dim3(32, 8), 0, stream>>>(
        canvas, kern, epsd, epsp, epsr, out);
}